// Round 6
// baseline (1596.222 us; speedup 1.0000x reference)
//
#include <hip/hip_runtime.h>
#include <hip/hip_bf16.h>
#include <cstdio>
#include <cstdint>

typedef __hip_bfloat16 bf16;
typedef __attribute__((ext_vector_type(8)))  short short8v;  // 8 bf16 = 4 VGPR (MFMA A/B frag)
typedef __attribute__((ext_vector_type(4)))  float f32x4;    // MFMA C/D frag

static __device__ __forceinline__ float b2f(bf16 v){ return __bfloat162float(v); }
static __device__ __forceinline__ bf16  f2b(float v){ return __float2bfloat16(v); }
static __device__ __forceinline__ float ldf(const float* p){ return *p; }
static __device__ __forceinline__ float ldf(const bf16* p){ return b2f(*p); }

// bf16-pair helpers: u32 = [hi:lo] two consecutive bf16; bf16->f32 is exact bit-shift
static __device__ __forceinline__ float bl(uint32_t u){ union{uint32_t i; float f;} c; c.i = u<<16;          return c.f; }
static __device__ __forceinline__ float bh(uint32_t u){ union{uint32_t i; float f;} c; c.i = u & 0xffff0000u; return c.f; }
static __device__ __forceinline__ uint32_t pk(float lo, float hi){
  bf16 a=f2b(lo), b=f2b(hi);
  uint16_t ai=*reinterpret_cast<uint16_t*>(&a), bi=*reinterpret_cast<uint16_t*>(&b);
  return ((uint32_t)bi<<16) | ai;
}
static __device__ __forceinline__ void ld2(const bf16* p, unsigned i32, float& lo, float& hi){
  uint32_t u = reinterpret_cast<const uint32_t*>(p)[i32]; lo=bl(u); hi=bh(u);
}
static __device__ __forceinline__ void ld2(const float* p, unsigned i32, float& lo, float& hi){
  float2 v = reinterpret_cast<const float2*>(p)[i32]; lo=v.x; hi=v.y;
}
static __device__ __forceinline__ void st2(bf16* p, unsigned i32, float lo, float hi){
  reinterpret_cast<uint32_t*>(p)[i32] = pk(lo,hi);
}
static __device__ __forceinline__ void st2(float* p, unsigned i32, float lo, float hi){
  reinterpret_cast<float2*>(p)[i32] = make_float2(lo,hi);
}

// ---------------- graph prep ----------------

__global__ void k_count(const int* __restrict__ dst, int* __restrict__ deg, int E){
  int e = blockIdx.x*256 + threadIdx.x;
  if(e<E) atomicAdd(&deg[dst[e]], 1);
}

__global__ void k_scan1(const int* __restrict__ deg, int* __restrict__ rp1, int* __restrict__ bsums, int N){
  __shared__ int s[256];
  int i = blockIdx.x*256 + threadIdx.x;
  int v = (i<N)? deg[i] : 0;
  s[threadIdx.x]=v; __syncthreads();
  for(int off=1; off<256; off<<=1){
    int t = (threadIdx.x>=off)? s[threadIdx.x-off] : 0;
    __syncthreads();
    s[threadIdx.x]+=t;
    __syncthreads();
  }
  if(i<N) rp1[i]=s[threadIdx.x];
  if(threadIdx.x==255) bsums[blockIdx.x]=s[255];
}

__global__ void k_scan2(const int* __restrict__ bsums, int* __restrict__ boffs, int NB){
  __shared__ int s[512];
  int x=threadIdx.x;
  int v = (x<NB)? bsums[x] : 0;
  s[x]=v; __syncthreads();
  for(int off=1; off<512; off<<=1){
    int t=(x>=off)? s[x-off]:0; __syncthreads();
    s[x]+=t; __syncthreads();
  }
  if(x<NB) boffs[x]=s[x]-v;  // exclusive prefix
}

__global__ void k_scan3(int* __restrict__ row_ptr, const int* __restrict__ boffs,
                        const int* __restrict__ deg, float* __restrict__ dis, float* __restrict__ dinv, int N){
  int i = blockIdx.x*256+threadIdx.x;
  if(i<N){
    row_ptr[i+1] += boffs[blockIdx.x];
    int d = deg[i];
    dis[i]  = (d>0)? rsqrtf((float)d) : 0.f;
    dinv[i] = (d>0)? sqrtf((float)d)  : 0.f;
    if(i==0) row_ptr[0]=0;
  }
}

// legacy 1-pass fill (fallback when nbuk>1600): 15x write-amp measured (197MB vs 12.8MB ideal)
__global__ void k_fill(const int* __restrict__ src, const int* __restrict__ dst,
                       const int* __restrict__ row_ptr, int* __restrict__ deg,
                       int* __restrict__ csr_src, int E){
  int e = blockIdx.x*256+threadIdx.x;
  if(e<E){
    int d = dst[e];
    int pos = row_ptr[d] + atomicAdd(&deg[d],-1) - 1;
    csr_src[pos] = src[e];
  }
}

// ---- bucketed CSR fill (kills the 15x write-amp: all scatters land L2-local) ----
// buckets = dst>>6 (64 nodes each); 256 edge-chunks; per-(bucket,chunk) exclusive
// regions from a 2-level scan -> k_bscat needs only LDS cursors, writes fill lines densely.

__global__ void k_hist(const int* __restrict__ dst, int* __restrict__ chunk_hist,
                       int* __restrict__ btot, int E, int nbuk, int epc){
  __shared__ int h[1600];
  for(int i=threadIdx.x;i<nbuk;i+=256) h[i]=0;
  __syncthreads();
  int base=blockIdx.x*epc, end=min(base+epc,E);
  for(int e=base+(int)threadIdx.x; e<end; e+=256) atomicAdd(&h[dst[e]>>6],1);
  __syncthreads();
  for(int i=threadIdx.x;i<nbuk;i+=256){
    int hv=h[i];
    chunk_hist[(size_t)i*256 + blockIdx.x]=hv;     // bucket-major [nbuk][256]
    if(hv) atomicAdd(&btot[i],hv);
  }
}

// bbase[i] = global exclusive prefix of btot  (binc = k_scan1 inclusive, boffs = block offsets)
__global__ void k_bfix(const int* __restrict__ binc, const int* __restrict__ btot,
                       const int* __restrict__ boffs, int* __restrict__ bbase, int nbuk){
  int i=blockIdx.x*256+threadIdx.x;
  if(i<nbuk) bbase[i] = binc[i] + boffs[i>>8] - btot[i];
}

// in-place: chunk_hist[i][c] -> bbase[i] + sum_{c'<c} chunk_hist[i][c']
__global__ void k_cscan(int* __restrict__ chunk_hist, const int* __restrict__ bbase, int nbuk){
  __shared__ int s[256];
  int b=blockIdx.x; if(b>=nbuk) return;
  int x=threadIdx.x;
  int v=chunk_hist[(size_t)b*256+x];
  s[x]=v; __syncthreads();
  for(int off=1; off<256; off<<=1){
    int t=(x>=off)? s[x-off]:0; __syncthreads();
    s[x]+=t; __syncthreads();
  }
  chunk_hist[(size_t)b*256+x] = s[x]-v + bbase[b];
}

__global__ void k_bscat(const int* __restrict__ src, const int* __restrict__ dst,
                        const int* __restrict__ cbase, uint2* __restrict__ ebuf,
                        int E, int nbuk, int epc){
  __shared__ int cur[1600];
  for(int i=threadIdx.x;i<nbuk;i+=256) cur[i]=cbase[(size_t)i*256 + blockIdx.x];
  __syncthreads();
  int base=blockIdx.x*epc, end=min(base+epc,E);
  for(int e=base+(int)threadIdx.x; e<end; e+=256){
    int d=dst[e], s=src[e];
    int p=atomicAdd(&cur[d>>6],1);                 // LDS atomic, chunk-private region
    ebuf[p]=make_uint2((unsigned)s,(unsigned)d);
  }
}

// edges now dst-bucket-ordered: csr scatter + deg countdown stay in a rolling L2 window
__global__ void k_fill2(const uint2* __restrict__ ebuf, const int* __restrict__ row_ptr,
                        int* __restrict__ deg, int* __restrict__ csr_src, int E){
  int e = blockIdx.x*256+threadIdx.x;
  if(e<E){
    uint2 p = ebuf[e];
    int d=(int)p.y;
    int pos = row_ptr[d] + atomicAdd(&deg[d],-1) - 1;
    csr_src[pos] = (int)p.x;
  }
}

// -------- weight prep: f32 [K][64] -> bf16 WT [64][Kp] (transposed, padded) --------
__global__ void k_prep(const float* __restrict__ W0, const float* __restrict__ Ws0,
                       const float* __restrict__ W1, const float* __restrict__ Ws1,
                       const float* __restrict__ W2, const float* __restrict__ Ws2,
                       const float* __restrict__ Wmix,
                       bf16* __restrict__ WT0, bf16* __restrict__ WT1,
                       bf16* __restrict__ WT2, bf16* __restrict__ WTm){
  int idx = blockIdx.x*256 + threadIdx.x;
  if(idx < 57344){                                   // layer0, K=128, Kp=136
    int w = idx >> 13, r = idx & 8191;
    int k = r >> 6, n = r & 63;
    float v = (w==0)? Ws0[(k<<6)+n] : W0[(((6-w)<<7) + k)*64 + n];
    WT0[(size_t)((w<<6)+n)*136 + k] = f2b(v);
  } else if(idx < 57344+28672){                      // layer1, K=64, Kp=72
    int i2 = idx - 57344;
    int w = i2 >> 12, r = i2 & 4095;
    int k = r >> 6, n = r & 63;
    float v = (w==0)? Ws1[(k<<6)+n] : W1[(((6-w)<<6) + k)*64 + n];
    WT1[(size_t)((w<<6)+n)*72 + k] = f2b(v);
  } else if(idx < 57344+2*28672){                    // layer2
    int i2 = idx - (57344+28672);
    int w = i2 >> 12, r = i2 & 4095;
    int k = r >> 6, n = r & 63;
    float v = (w==0)? Ws2[(k<<6)+n] : W2[(((6-w)<<6) + k)*64 + n];
    WT2[(size_t)((w<<6)+n)*72 + k] = f2b(v);
  } else if(idx < 57344+2*28672+12288){              // mix, K=192, Kp=200
    int i2 = idx - (57344+2*28672);
    int n = i2 / 192, k = i2 % 192;
    float v = (n<32)? Wmix[k*32 + n] : Wmix[6144 + k*32 + (n-32)];
    WTm[(size_t)n*200 + k] = f2b(v);
  }
}

// -------- MFMA mega-GEMM: BM=128, 4 waves (2x2), wave-tile 64x32, 16x16x32 bf16 --------
template<int K, int NW, int AMODE>
__global__ __launch_bounds__(256,2) void k_mfma(
    const bf16* __restrict__ Ab, const float* __restrict__ Af, const bf16* __restrict__ WT,
    bf16* __restrict__ O0, bf16* __restrict__ O1, bf16* __restrict__ O2, bf16* __restrict__ O3,
    bf16* __restrict__ O4, bf16* __restrict__ O5, bf16* __restrict__ O6,
    float* __restrict__ Zf, const float* __restrict__ dis, int M)
{
  constexpr int Kp = K + 8;
  static_assert(Kp % 8 == 0, "Kp must keep 16B alignment");
  constexpr int NS = K / 32;                 // K-slices per MFMA chain
  constexpr int NSLOT = (NW>1) ? 2 : 1;
  __shared__ short sA[128][Kp];
  __shared__ short sW[NSLOT][64][Kp];

  const int t    = threadIdx.x;
  const int m0   = blockIdx.x * 128;
  const int l    = t & 63;
  const int wid  = t >> 6;
  const int wrow = (wid >> 1) * 64;          // wave row base in tile
  const int wcol = (wid & 1) * 32;           // wave col base
  const int l4   = l & 15;
  const int lk8  = (l >> 4) * 8;             // contiguous-8 k sub-offset (m97-verified layout)

  bf16* const Ol[7] = {O0,O1,O2,O3,O4,O5,O6};
  const short8v szero = {0,0,0,0,0,0,0,0};
  const f32x4   fzero = {0.f,0.f,0.f,0.f};

  constexpr int WCH = (64*Kp)/8;             // 16B chunks per W tile
  constexpr int WIT = (WCH + 255)/256;
  short8v wreg[WIT];
  auto loadW = [&](int w){
    #pragma unroll
    for(int it=0; it<WIT; ++it){
      int c = t + it*256;
      if(c < WCH) wreg[it] = *reinterpret_cast<const short8v*>(&WT[(size_t)w*(64*Kp) + (size_t)c*8]);
    }
  };
  auto writeW = [&](int slot){
    short* base = &sW[slot][0][0];
    #pragma unroll
    for(int it=0; it<WIT; ++it){
      int c = t + it*256;
      if(c < WCH) *reinterpret_cast<short8v*>(base + (size_t)c*8) = wreg[it];
    }
  };

  loadW(0);   // global loads in flight while we stage A

  {
    constexpr int CPR = K/8;                 // 16B chunks per row
    #pragma unroll
    for(int it=0; it<(128*CPR)/256; ++it){
      int c = t + it*256;
      int row = c / CPR, j = c % CPR;
      int m = m0 + row;
      short8v v = szero;
      if(m < M){
        if constexpr(AMODE==0){
          v = *reinterpret_cast<const short8v*>(&Ab[(size_t)m*K + j*8]);
        } else if constexpr(AMODE==1){
          float4 f0 = *reinterpret_cast<const float4*>(&Af[(size_t)m*K + j*8]);
          float4 f1 = *reinterpret_cast<const float4*>(&Af[(size_t)m*K + j*8 + 4]);
          bf16* hp = reinterpret_cast<bf16*>(&v);
          hp[0]=f2b(f0.x); hp[1]=f2b(f0.y); hp[2]=f2b(f0.z); hp[3]=f2b(f0.w);
          hp[4]=f2b(f1.x); hp[5]=f2b(f1.y); hp[6]=f2b(f1.z); hp[7]=f2b(f1.w);
        } else {                             // mix: j<8 -> hA (64 bf16), else x (128 f32)
          if(j < 8){
            v = *reinterpret_cast<const short8v*>(&Ab[(size_t)m*64 + j*8]);
          } else {
            float4 f0 = *reinterpret_cast<const float4*>(&Af[(size_t)m*128 + (j-8)*8]);
            float4 f1 = *reinterpret_cast<const float4*>(&Af[(size_t)m*128 + (j-8)*8 + 4]);
            bf16* hp = reinterpret_cast<bf16*>(&v);
            hp[0]=f2b(f0.x); hp[1]=f2b(f0.y); hp[2]=f2b(f0.z); hp[3]=f2b(f0.w);
            hp[4]=f2b(f1.x); hp[5]=f2b(f1.y); hp[6]=f2b(f1.z); hp[7]=f2b(f1.w);
          }
        }
      }
      *reinterpret_cast<short8v*>(&sA[row][j*8]) = v;
    }
  }

  writeW(0);
  __syncthreads();

  short8v af[4][(NS>0)?NS:1];
  if constexpr(NW > 1){
    #pragma unroll
    for(int rt=0; rt<4; ++rt)
      #pragma unroll
      for(int s=0; s<NS; ++s)
        af[rt][s] = *reinterpret_cast<const short8v*>(&sA[wrow + rt*16 + l4][s*32 + lk8]);
  }

  #pragma unroll
  for(int w=0; w<NW; ++w){
    if(w+1 < NW) loadW(w+1);                 // issue early; consumed by writeW after compute

    f32x4 acc[4][2];
    #pragma unroll
    for(int rt=0; rt<4; ++rt){ acc[rt][0]=fzero; acc[rt][1]=fzero; }

    const short* wb = &sW[(NW>1)?(w&1):0][0][0];
    #pragma unroll
    for(int s=0; s<NS; ++s){
      short8v b0 = *reinterpret_cast<const short8v*>(wb + (size_t)(wcol +      l4)*Kp + s*32 + lk8);
      short8v b1 = *reinterpret_cast<const short8v*>(wb + (size_t)(wcol + 16 + l4)*Kp + s*32 + lk8);
      #pragma unroll
      for(int rt=0; rt<4; ++rt){
        short8v a = (NW>1) ? af[rt][s]
                  : *reinterpret_cast<const short8v*>(&sA[wrow + rt*16 + l4][s*32 + lk8]);
        acc[rt][0] = __builtin_amdgcn_mfma_f32_16x16x32_bf16(a, b0, acc[rt][0], 0,0,0);
        acc[rt][1] = __builtin_amdgcn_mfma_f32_16x16x32_bf16(a, b1, acc[rt][1], 0,0,0);
      }
    }

    if(w+1 < NW){ writeW((w+1)&1); __syncthreads(); }

    // ---- store (C/D: col = l&15, row = (l>>4)*4 + reg  [m89/m91-verified]) ----
    #pragma unroll
    for(int rt=0; rt<4; ++rt){
      #pragma unroll
      for(int r=0; r<4; ++r){
        int row = m0 + wrow + rt*16 + ((l>>4)<<2) + r;
        if(row < M){
          if constexpr(AMODE != 2){
            float sc = 1.f;
            if(NW>1 && w==1) sc = dis[row];  // P0s is the dis-scaled gather twin
            #pragma unroll
            for(int ct=0; ct<2; ++ct){
              float vv = acc[rt][ct][r] * sc;
              Ol[w][(size_t)row*64 + wcol + ct*16 + l4] = f2b(vv);
            }
          } else {                            // mix: cols 0..31 -> Zf (f32); 32..63 -> O0 bf16 *dis
            float dm = dis[row];
            #pragma unroll
            for(int ct=0; ct<2; ++ct){
              int col = wcol + ct*16 + l4;
              float vv = acc[rt][ct][r];
              if(col < 32) Zf[(size_t)row*32 + col] = vv;
              else         O0[(size_t)row*32 + (col-32)] = f2b(vv*dm);
            }
          }
        }
      }
    }
  }
}

// ---------------- sparse prop + Clenshaw combine ----------------
// MODE 0: r = Z - 2a                         -> store SCALED (dis[v]*r)
// MODE 1: r = Z - 2a - BsubS*dinv            -> store SCALED
// MODE 2: r = relu(Z - a - BsubS*dinv + bias) + Zs + bias2 -> store normal bf16
// MODE 3: r = Z - a + bias                   -> store normal f32
template<int F, int MODE, typename ZT, typename OT>
__global__ __launch_bounds__(256) void k_prop(const int* __restrict__ row_ptr, const int* __restrict__ csr_src,
    const float* __restrict__ dis, const float* __restrict__ dinv, const bf16* __restrict__ BinS,
    const ZT* __restrict__ Z, const bf16* __restrict__ BsubS,
    const float* __restrict__ bias, const bf16* __restrict__ Zs, const float* __restrict__ bias2,
    OT* __restrict__ out, int N){
  constexpr int L   = F/2;          // lanes per node (feature pairs)
  constexpr int NPB = 256/L;        // nodes per block
  int v = blockIdx.x*NPB + threadIdx.x/L;
  if(v>=N) return;
  int f2 = threadIdx.x % L;
  const uint32_t* __restrict__ B32 = reinterpret_cast<const uint32_t*>(BinS);
  int e0=row_ptr[v], e1=row_ptr[v+1];
  unsigned idx32 = (unsigned)v*L + f2;

  // issue epilogue loads early — independent of gathers, latency overlaps
  float zL, zH; ld2(Z, idx32, zL, zH);
  float bsL=0.f, bsH=0.f;
  if constexpr(MODE==1 || MODE==2){
    uint32_t bu = reinterpret_cast<const uint32_t*>(BsubS)[idx32]; bsL=bl(bu); bsH=bh(bu);
  }
  float biL=0.f, biH=0.f;
  if constexpr(MODE>=2){
    float2 bv = reinterpret_cast<const float2*>(bias)[f2]; biL=bv.x; biH=bv.y;
  }
  float zsL=0.f, zsH=0.f, b2L=0.f, b2H=0.f;
  if constexpr(MODE==2){
    uint32_t su = reinterpret_cast<const uint32_t*>(Zs)[idx32]; zsL=bl(su); zsH=bh(su);
    float2 b2v = reinterpret_cast<const float2*>(bias2)[f2]; b2L=b2v.x; b2H=b2v.y;
  }
  float dv = dis[v];
  float di = dinv[v];

  float aL=0.f, aH=0.f;
  int e=e0;
  // main: L edges per iteration, ONE coalesced index load, distribute via shfl
  for(; e+L<=e1; e+=L){
    int si = csr_src[e + f2];
    #pragma unroll
    for(int c=0; c<L/16; ++c){
      int s[16];
      #pragma unroll
      for(int j=0;j<16;++j) s[j] = __shfl(si, c*16+j, L);
      uint32_t u[16];
      #pragma unroll
      for(int j=0;j<16;++j) u[j]=B32[(unsigned)s[j]*L + f2];
      #pragma unroll
      for(int j=0;j<16;++j){ aL+=bl(u[j]); aH+=bh(u[j]); }
    }
  }
  // remainder (< L edges): broadcast-load path
  if(e+16<=e1){
    int s[16];
    #pragma unroll
    for(int j=0;j<16;++j) s[j]=csr_src[e+j];
    uint32_t u[16];
    #pragma unroll
    for(int j=0;j<16;++j) u[j]=B32[(unsigned)s[j]*L + f2];
    #pragma unroll
    for(int j=0;j<16;++j){ aL+=bl(u[j]); aH+=bh(u[j]); }
    e+=16;
  }
  if(e+8<=e1){
    int s[8];
    #pragma unroll
    for(int j=0;j<8;++j) s[j]=csr_src[e+j];
    uint32_t u[8];
    #pragma unroll
    for(int j=0;j<8;++j) u[j]=B32[(unsigned)s[j]*L + f2];
    #pragma unroll
    for(int j=0;j<8;++j){ aL+=bl(u[j]); aH+=bh(u[j]); }
    e+=8;
  }
  if(e<e1){
    #pragma unroll
    for(int j=0;j<8;++j){
      int idx=e+j;
      int s=csr_src[idx<e1 ? idx : e0];
      uint32_t uu=B32[(unsigned)s*L + f2];
      if(idx<e1){ aL+=bl(uu); aH+=bh(uu); }
    }
  }
  aL*=dv; aH*=dv;                 // a = dis[v] * sum (BinS pre-scaled by dis[src])
  float rL, rH;
  if constexpr(MODE==0){ rL = zL - 2.f*aL;              rH = zH - 2.f*aH; }
  else if constexpr(MODE==1){ rL = zL - 2.f*aL - bsL*di; rH = zH - 2.f*aH - bsH*di; }
  else if constexpr(MODE==2){
    float tL = zL - aL - bsL*di + biL;
    float tH = zH - aH - bsH*di + biH;
    rL = fmaxf(tL,0.f) + zsL + b2L;
    rH = fmaxf(tH,0.f) + zsH + b2H;
  } else { rL = zL - aL + biL; rH = zH - aH + biH; }
  if constexpr(MODE<=1) st2(out, idx32, dv*rL, dv*rH);   // scaled store (single stream)
  else                  st2(out, idx32, rL, rH);
}

// ---------------- host ----------------

extern "C" void kernel_launch(void* const* d_in, const int* in_sizes, int n_in,
                              void* d_out, int out_size, void* d_ws, size_t ws_size,
                              hipStream_t stream) {
  const int N = in_sizes[0]/128;     // 100000
  const int E = in_sizes[1]/2;       // 3200000

  const float* x    = (const float*)d_in[0];
  const int*   ei   = (const int*  )d_in[1];
  const float* W0   = (const float*)d_in[2];
  const float* b0   = (const float*)d_in[3];
  const float* Ws0  = (const float*)d_in[4];
  const float* bs0  = (const float*)d_in[5];
  const float* W1   = (const float*)d_in[6];
  const float* b1   = (const float*)d_in[7];
  const float* Ws1  = (const float*)d_in[8];
  const float* bs1  = (const float*)d_in[9];
  const float* W2   = (const float*)d_in[10];
  const float* b2   = (const float*)d_in[11];
  const float* Ws2  = (const float*)d_in[12];
  const float* bs2  = (const float*)d_in[13];
  const float* Wmix = (const float*)d_in[14];
  const float* bmix = (const float*)d_in[15];
  float* out = (float*)d_out;

  const int* src = ei;
  const int* dst = ei + E;

  size_t off=0;
  char* ws=(char*)d_ws;
  auto alloc=[&](size_t bytes)->void*{ void* p = ws+off; off=(off+bytes+255)&~(size_t)255; return p; };
  int*   csr_src = (int*)  alloc((size_t)E*4);
  int*   row_ptr = (int*)  alloc((size_t)(N+1)*4);
  int*   deg     = (int*)  alloc((size_t)N*4);
  float* dis     = (float*)alloc((size_t)N*4);
  float* dinv    = (float*)alloc((size_t)N*4);
  int*   bsums   = (int*)  alloc(2048);
  int*   boffs   = (int*)  alloc(2048);
  bf16*  Z0      = (bf16*) alloc((size_t)N*64*2);
  bf16*  Z1      = (bf16*) alloc((size_t)N*64*2);  // reused as f32 N*32 for mix Z0
  bf16*  Z2      = (bf16*) alloc((size_t)N*64*2);
  bf16*  Z3      = (bf16*) alloc((size_t)N*64*2);
  bf16*  Z4      = (bf16*) alloc((size_t)N*64*2);
  bf16*  Zsb     = (bf16*) alloc((size_t)N*64*2);
  bf16*  P0s     = (bf16*) alloc((size_t)N*64*2);
  bf16*  P1s     = (bf16*) alloc((size_t)N*64*2);
  bf16*  P2s     = (bf16*) alloc((size_t)N*64*2);
  bf16*  hA      = (bf16*) alloc((size_t)N*64*2);
  bf16*  hB      = (bf16*) alloc((size_t)N*64*2);
  bf16*  WT0     = (bf16*) alloc((size_t)7*64*136*2);   // layer0 weights, transposed+padded bf16
  bf16*  WT1     = (bf16*) alloc((size_t)7*64*72*2);
  bf16*  WT2     = (bf16*) alloc((size_t)7*64*72*2);
  bf16*  WTm     = (bf16*) alloc((size_t)64*200*2);
  if(off > ws_size){
    fprintf(stderr, "kernel_launch: workspace too small: need %zu, have %zu\n", off, ws_size);
    return;
  }

  const int NB   = (N+255)/256;
  const int gE   = (E+255)/256;
  const int gM   = (N+127)/128;
  const int gP64 = (N+7)/8;      // k_prop<64>: 32 lanes/node, 8 nodes/block
  const int gP32 = (N+15)/16;    // k_prop<32>: 16 lanes/node, 16 nodes/block

  // bucketed-fill scratch: overlays Z0..Z2 (written only before first GEMM output)
  const int nbuk = (N+63)>>6;
  const int NB2  = (nbuk+255)/256;
  const int epc  = (E+255)/256;
  const bool fast_fill = (nbuk <= 1600);
  char*  gs         = (char*)Z0;
  uint2* ebuf       = (uint2*)gs;
  int*   chunk_hist = (int*)(gs + (((size_t)E*8 + 255) & ~(size_t)255));
  int*   binc       = chunk_hist + (size_t)nbuk*256;
  int*   btot       = binc + nbuk;
  int*   bbase      = btot + nbuk;

  // weight prep (independent of graph data)
  k_prep<<<496,256,0,stream>>>(W0,Ws0,W1,Ws1,W2,Ws2,Wmix, WT0,WT1,WT2,WTm);

  // graph prep
  hipMemsetAsync(deg, 0, (size_t)N*4, stream);
  k_count<<<gE,256,0,stream>>>(dst, deg, E);
  if(fast_fill){
    hipMemsetAsync(btot, 0, (size_t)nbuk*4, stream);
    k_hist<<<256,256,0,stream>>>(dst, chunk_hist, btot, E, nbuk, epc);
    k_scan1<<<NB2,256,0,stream>>>(btot, binc, bsums, nbuk);
    k_scan2<<<1,512,0,stream>>>(bsums, boffs, NB2);
    k_bfix<<<NB2,256,0,stream>>>(binc, btot, boffs, bbase, nbuk);
    k_cscan<<<nbuk,256,0,stream>>>(chunk_hist, bbase, nbuk);
  }
  k_scan1<<<NB,256,0,stream>>>(deg, row_ptr+1, bsums, N);
  k_scan2<<<1,512,0,stream>>>(bsums, boffs, NB);
  k_scan3<<<NB,256,0,stream>>>(row_ptr, boffs, deg, dis, dinv, N);
  if(fast_fill){
    k_bscat<<<256,256,0,stream>>>(src, dst, chunk_hist, ebuf, E, nbuk, epc);
    k_fill2<<<gE,256,0,stream>>>(ebuf, row_ptr, deg, csr_src, E);
  } else {
    k_fill<<<gE,256,0,stream>>>(src, dst, row_ptr, deg, csr_src, E);
  }

  auto PROPS=[&](const float* b, const float* bs_, bf16* hout){
    k_prop<64,0,bf16,bf16><<<gP64,256,0,stream>>>(row_ptr,csr_src,dis,dinv,P0s,Z4,nullptr,nullptr,nullptr,nullptr,P1s,N); // B4
    k_prop<64,1,bf16,bf16><<<gP64,256,0,stream>>>(row_ptr,csr_src,dis,dinv,P1s,Z3,P0s,nullptr,nullptr,nullptr,P2s,N);     // B3
    k_prop<64,1,bf16,bf16><<<gP64,256,0,stream>>>(row_ptr,csr_src,dis,dinv,P2s,Z2,P1s,nullptr,nullptr,nullptr,P0s,N);     // B2
    k_prop<64,1,bf16,bf16><<<gP64,256,0,stream>>>(row_ptr,csr_src,dis,dinv,P0s,Z1,P2s,nullptr,nullptr,nullptr,P1s,N);     // B1
    k_prop<64,2,bf16,bf16><<<gP64,256,0,stream>>>(row_ptr,csr_src,dis,dinv,P1s,Z0,P0s,b,Zsb,bs_,hout,N);                  // h'
  };

  // layer 0: A = x (f32, cvt on the fly), K=128
  k_mfma<128,7,1><<<gM,256,0,stream>>>(nullptr, x, WT0, Zsb,P0s,Z4,Z3,Z2,Z1,Z0, nullptr, dis, N);
  PROPS(b0, bs0, hA);
  // layer 1: A = hA bf16, K=64
  k_mfma<64,7,0><<<gM,256,0,stream>>>(hA, nullptr, WT1, Zsb,P0s,Z4,Z3,Z2,Z1,Z0, nullptr, dis, N);
  PROPS(b1, bs1, hB);
  // layer 2
  k_mfma<64,7,0><<<gM,256,0,stream>>>(hB, nullptr, WT2, Zsb,P0s,Z4,Z3,Z2,Z1,Z0, nullptr, dis, N);
  PROPS(b2, bs2, hA);

  // mix head: A = [hA | x] (K=192); cols 0..31 -> Zmixf (f32), cols 32..63 -> P0s (bf16, *dis)
  float* Zmixf = (float*)Z1;   // Z1 free after layer-2 props
  k_mfma<192,1,2><<<gM,256,0,stream>>>(hA, x, WTm, P0s,nullptr,nullptr,nullptr,nullptr,nullptr,nullptr, Zmixf, dis, N);
  k_prop<32,3,float,float><<<gP32,256,0,stream>>>(row_ptr,csr_src,dis,dinv,P0s,Zmixf,nullptr,bmix,nullptr,nullptr,out,N);
}

// Round 8
// 1380.541 us; speedup vs baseline: 1.1562x; 1.1562x over previous
//
#include <hip/hip_runtime.h>
#include <hip/hip_bf16.h>
#include <cstdio>
#include <cstdint>

typedef __hip_bfloat16 bf16;
typedef __attribute__((ext_vector_type(8)))  short short8v;  // 8 bf16 = 4 VGPR (MFMA A/B frag)
typedef __attribute__((ext_vector_type(4)))  float f32x4;    // MFMA C/D frag

static __device__ __forceinline__ float b2f(bf16 v){ return __bfloat162float(v); }
static __device__ __forceinline__ bf16  f2b(float v){ return __float2bfloat16(v); }
static __device__ __forceinline__ float ldf(const float* p){ return *p; }
static __device__ __forceinline__ float ldf(const bf16* p){ return b2f(*p); }

// bf16-pair helpers: u32 = [hi:lo] two consecutive bf16; bf16->f32 is exact bit-shift
static __device__ __forceinline__ float bl(uint32_t u){ union{uint32_t i; float f;} c; c.i = u<<16;          return c.f; }
static __device__ __forceinline__ float bh(uint32_t u){ union{uint32_t i; float f;} c; c.i = u & 0xffff0000u; return c.f; }
static __device__ __forceinline__ uint32_t pk(float lo, float hi){
  bf16 a=f2b(lo), b=f2b(hi);
  uint16_t ai=*reinterpret_cast<uint16_t*>(&a), bi=*reinterpret_cast<uint16_t*>(&b);
  return ((uint32_t)bi<<16) | ai;
}
static __device__ __forceinline__ void ld2(const bf16* p, unsigned i32, float& lo, float& hi){
  uint32_t u = reinterpret_cast<const uint32_t*>(p)[i32]; lo=bl(u); hi=bh(u);
}
static __device__ __forceinline__ void ld2(const float* p, unsigned i32, float& lo, float& hi){
  float2 v = reinterpret_cast<const float2*>(p)[i32]; lo=v.x; hi=v.y;
}
static __device__ __forceinline__ void st2(bf16* p, unsigned i32, float lo, float hi){
  reinterpret_cast<uint32_t*>(p)[i32] = pk(lo,hi);
}
static __device__ __forceinline__ void st2(float* p, unsigned i32, float lo, float hi){
  reinterpret_cast<float2*>(p)[i32] = make_float2(lo,hi);
}

// ---------------- graph prep ----------------
// [measured r5/r6]: 3.2M random global atomics cost ~128-162us each kernel and ~31B HBM
// write per atomic (k_count: 99.8MB WRITE vs 400KB ideal). Fast path below has ZERO
// global atomics: bucket-sort edges (LDS cursors), then per-bucket LDS histograms/cursors.

// legacy pair (fallback when nbuk>1600)
__global__ void k_count(const int* __restrict__ dst, int* __restrict__ deg, int E){
  int e = blockIdx.x*256 + threadIdx.x;
  if(e<E) atomicAdd(&deg[dst[e]], 1);
}
__global__ void k_fill(const int* __restrict__ src, const int* __restrict__ dst,
                       const int* __restrict__ row_ptr, int* __restrict__ deg,
                       int* __restrict__ csr_src, int E){
  int e = blockIdx.x*256+threadIdx.x;
  if(e<E){
    int d = dst[e];
    int pos = row_ptr[d] + atomicAdd(&deg[d],-1) - 1;
    csr_src[pos] = src[e];
  }
}

__global__ void k_scan1(const int* __restrict__ deg, int* __restrict__ rp1, int* __restrict__ bsums, int N){
  __shared__ int s[256];
  int i = blockIdx.x*256 + threadIdx.x;
  int v = (i<N)? deg[i] : 0;
  s[threadIdx.x]=v; __syncthreads();
  for(int off=1; off<256; off<<=1){
    int t = (threadIdx.x>=off)? s[threadIdx.x-off] : 0;
    __syncthreads();
    s[threadIdx.x]+=t;
    __syncthreads();
  }
  if(i<N) rp1[i]=s[threadIdx.x];
  if(threadIdx.x==255) bsums[blockIdx.x]=s[255];
}

__global__ void k_scan2(const int* __restrict__ bsums, int* __restrict__ boffs, int NB){
  __shared__ int s[512];
  int x=threadIdx.x;
  int v = (x<NB)? bsums[x] : 0;
  s[x]=v; __syncthreads();
  for(int off=1; off<512; off<<=1){
    int t=(x>=off)? s[x-off]:0; __syncthreads();
    s[x]+=t; __syncthreads();
  }
  if(x<NB) boffs[x]=s[x]-v;  // exclusive prefix
}

__global__ void k_scan3(int* __restrict__ row_ptr, const int* __restrict__ boffs,
                        const int* __restrict__ deg, float* __restrict__ dis, float* __restrict__ dinv, int N){
  int i = blockIdx.x*256+threadIdx.x;
  if(i<N){
    row_ptr[i+1] += boffs[blockIdx.x];
    int d = deg[i];
    dis[i]  = (d>0)? rsqrtf((float)d) : 0.f;
    dinv[i] = (d>0)? sqrtf((float)d)  : 0.f;
    if(i==0) row_ptr[0]=0;
  }
}

// buckets = dst>>6 (64 nodes each); 256 edge-chunks; per-(bucket,chunk) exclusive regions
__global__ void k_hist(const int* __restrict__ dst, int* __restrict__ chunk_hist,
                       int* __restrict__ btot, int E, int nbuk, int epc){
  __shared__ int h[1600];
  for(int i=threadIdx.x;i<nbuk;i+=256) h[i]=0;
  __syncthreads();
  int base=blockIdx.x*epc, end=min(base+epc,E);
  for(int e=base+(int)threadIdx.x; e<end; e+=256) atomicAdd(&h[dst[e]>>6],1);
  __syncthreads();
  for(int i=threadIdx.x;i<nbuk;i+=256){
    int hv=h[i];
    chunk_hist[(size_t)i*256 + blockIdx.x]=hv;     // bucket-major [nbuk][256]
    if(hv) atomicAdd(&btot[i],hv);
  }
}

// bbase[i] = global exclusive prefix of btot  (binc = k_scan1 inclusive, boffs = block offsets)
__global__ void k_bfix(const int* __restrict__ binc, const int* __restrict__ btot,
                       const int* __restrict__ boffs, int* __restrict__ bbase, int nbuk){
  int i=blockIdx.x*256+threadIdx.x;
  if(i<nbuk) bbase[i] = binc[i] + boffs[i>>8] - btot[i];
}

// in-place: chunk_hist[i][c] -> bbase[i] + sum_{c'<c} chunk_hist[i][c']
__global__ void k_cscan(int* __restrict__ chunk_hist, const int* __restrict__ bbase, int nbuk){
  __shared__ int s[256];
  int b=blockIdx.x; if(b>=nbuk) return;
  int x=threadIdx.x;
  int v=chunk_hist[(size_t)b*256+x];
  s[x]=v; __syncthreads();
  for(int off=1; off<256; off<<=1){
    int t=(x>=off)? s[x-off]:0; __syncthreads();
    s[x]+=t; __syncthreads();
  }
  chunk_hist[(size_t)b*256+x] = s[x]-v + bbase[b];
}

__global__ void k_bscat(const int* __restrict__ src, const int* __restrict__ dst,
                        const int* __restrict__ cbase, uint2* __restrict__ ebuf,
                        int E, int nbuk, int epc){
  __shared__ int cur[1600];
  for(int i=threadIdx.x;i<nbuk;i+=256) cur[i]=cbase[(size_t)i*256 + blockIdx.x];
  __syncthreads();
  int base=blockIdx.x*epc, end=min(base+epc,E);
  for(int e=base+(int)threadIdx.x; e<end; e+=256){
    int d=dst[e], s=src[e];
    int p=atomicAdd(&cur[d>>6],1);                 // LDS atomic, chunk-private region
    ebuf[p]=make_uint2((unsigned)s,(unsigned)d);
  }
}

// deg via per-bucket LDS histogram over the bucket's contiguous edge slice (no global atomics)
__global__ void k_degf(const uint2* __restrict__ ebuf, const int* __restrict__ bbase,
                       const int* __restrict__ btot, int* __restrict__ deg, int N){
  __shared__ int cnt[64];
  int b=blockIdx.x;
  if(threadIdx.x<64) cnt[threadIdx.x]=0;
  __syncthreads();
  int e0=bbase[b], e1=e0+btot[b];
  for(int e=e0+(int)threadIdx.x; e<e1; e+=256) atomicAdd(&cnt[ebuf[e].y & 63],1);
  __syncthreads();
  int n=b*64+(int)threadIdx.x;
  if(threadIdx.x<64 && n<N) deg[n]=cnt[threadIdx.x];
}

// CSR fill via per-bucket LDS cursors (no global atomics; writes land in the bucket's
// contiguous CSR region ~8KB -> dense write-back)
__global__ void k_fill3(const uint2* __restrict__ ebuf, const int* __restrict__ bbase,
                        const int* __restrict__ btot, const int* __restrict__ row_ptr,
                        int* __restrict__ csr_src, int N){
  __shared__ int cur[64];
  __shared__ int rp[64];
  int b=blockIdx.x;
  int n=b*64+(int)threadIdx.x;
  if(threadIdx.x<64){
    cur[threadIdx.x]=0;
    rp[threadIdx.x] = (n<N)? row_ptr[n] : 0;
  }
  __syncthreads();
  int e0=bbase[b], e1=e0+btot[b];
  for(int e=e0+(int)threadIdx.x; e<e1; e+=256){
    uint2 p=ebuf[e];
    int li=(int)(p.y & 63);
    int idx=atomicAdd(&cur[li],1);                 // LDS atomic
    csr_src[rp[li]+idx]=(int)p.x;
  }
}

// -------- weight prep: f32 [K][64] -> bf16 WT [64][Kp] (transposed, padded) --------
__global__ void k_prep(const float* __restrict__ W0, const float* __restrict__ Ws0,
                       const float* __restrict__ W1, const float* __restrict__ Ws1,
                       const float* __restrict__ W2, const float* __restrict__ Ws2,
                       const float* __restrict__ Wmix,
                       bf16* __restrict__ WT0, bf16* __restrict__ WT1,
                       bf16* __restrict__ WT2, bf16* __restrict__ WTm){
  int idx = blockIdx.x*256 + threadIdx.x;
  if(idx < 57344){                                   // layer0, K=128, Kp=136
    int w = idx >> 13, r = idx & 8191;
    int k = r >> 6, n = r & 63;
    float v = (w==0)? Ws0[(k<<6)+n] : W0[(((6-w)<<7) + k)*64 + n];
    WT0[(size_t)((w<<6)+n)*136 + k] = f2b(v);
  } else if(idx < 57344+28672){                      // layer1, K=64, Kp=72
    int i2 = idx - 57344;
    int w = i2 >> 12, r = i2 & 4095;
    int k = r >> 6, n = r & 63;
    float v = (w==0)? Ws1[(k<<6)+n] : W1[(((6-w)<<6) + k)*64 + n];
    WT1[(size_t)((w<<6)+n)*72 + k] = f2b(v);
  } else if(idx < 57344+2*28672){                    // layer2
    int i2 = idx - (57344+28672);
    int w = i2 >> 12, r = i2 & 4095;
    int k = r >> 6, n = r & 63;
    float v = (w==0)? Ws2[(k<<6)+n] : W2[(((6-w)<<6) + k)*64 + n];
    WT2[(size_t)((w<<6)+n)*72 + k] = f2b(v);
  } else if(idx < 57344+2*28672+12288){              // mix, K=192, Kp=200
    int i2 = idx - (57344+2*28672);
    int n = i2 / 192, k = i2 % 192;
    float v = (n<32)? Wmix[k*32 + n] : Wmix[6144 + k*32 + (n-32)];
    WTm[(size_t)n*200 + k] = f2b(v);
  }
}

// -------- MFMA mega-GEMM: BM=128, 4 waves (2x2), wave-tile 64x32, 16x16x32 bf16 --------
template<int K, int NW, int AMODE>
__global__ __launch_bounds__(256,2) void k_mfma(
    const bf16* __restrict__ Ab, const float* __restrict__ Af, const bf16* __restrict__ WT,
    bf16* __restrict__ O0, bf16* __restrict__ O1, bf16* __restrict__ O2, bf16* __restrict__ O3,
    bf16* __restrict__ O4, bf16* __restrict__ O5, bf16* __restrict__ O6,
    float* __restrict__ Zf, const float* __restrict__ dis, int M)
{
  constexpr int Kp = K + 8;
  static_assert(Kp % 8 == 0, "Kp must keep 16B alignment");
  constexpr int NS = K / 32;                 // K-slices per MFMA chain
  constexpr int NSLOT = (NW>1) ? 2 : 1;
  __shared__ short sA[128][Kp];
  __shared__ short sW[NSLOT][64][Kp];

  const int t    = threadIdx.x;
  const int m0   = blockIdx.x * 128;
  const int l    = t & 63;
  const int wid  = t >> 6;
  const int wrow = (wid >> 1) * 64;          // wave row base in tile
  const int wcol = (wid & 1) * 32;           // wave col base
  const int l4   = l & 15;
  const int lk8  = (l >> 4) * 8;             // contiguous-8 k sub-offset (m97-verified layout)

  bf16* const Ol[7] = {O0,O1,O2,O3,O4,O5,O6};
  const short8v szero = {0,0,0,0,0,0,0,0};
  const f32x4   fzero = {0.f,0.f,0.f,0.f};

  constexpr int WCH = (64*Kp)/8;             // 16B chunks per W tile
  constexpr int WIT = (WCH + 255)/256;
  short8v wreg[WIT];
  auto loadW = [&](int w){
    #pragma unroll
    for(int it=0; it<WIT; ++it){
      int c = t + it*256;
      if(c < WCH) wreg[it] = *reinterpret_cast<const short8v*>(&WT[(size_t)w*(64*Kp) + (size_t)c*8]);
    }
  };
  auto writeW = [&](int slot){
    short* base = &sW[slot][0][0];
    #pragma unroll
    for(int it=0; it<WIT; ++it){
      int c = t + it*256;
      if(c < WCH) *reinterpret_cast<short8v*>(base + (size_t)c*8) = wreg[it];
    }
  };

  loadW(0);   // global loads in flight while we stage A

  {
    constexpr int CPR = K/8;                 // 16B chunks per row
    #pragma unroll
    for(int it=0; it<(128*CPR)/256; ++it){
      int c = t + it*256;
      int row = c / CPR, j = c % CPR;
      int m = m0 + row;
      short8v v = szero;
      if(m < M){
        if constexpr(AMODE==0){
          v = *reinterpret_cast<const short8v*>(&Ab[(size_t)m*K + j*8]);
        } else if constexpr(AMODE==1){
          float4 f0 = *reinterpret_cast<const float4*>(&Af[(size_t)m*K + j*8]);
          float4 f1 = *reinterpret_cast<const float4*>(&Af[(size_t)m*K + j*8 + 4]);
          bf16* hp = reinterpret_cast<bf16*>(&v);
          hp[0]=f2b(f0.x); hp[1]=f2b(f0.y); hp[2]=f2b(f0.z); hp[3]=f2b(f0.w);
          hp[4]=f2b(f1.x); hp[5]=f2b(f1.y); hp[6]=f2b(f1.z); hp[7]=f2b(f1.w);
        } else {                             // mix: j<8 -> hA (64 bf16), else x (128 f32)
          if(j < 8){
            v = *reinterpret_cast<const short8v*>(&Ab[(size_t)m*64 + j*8]);
          } else {
            float4 f0 = *reinterpret_cast<const float4*>(&Af[(size_t)m*128 + (j-8)*8]);
            float4 f1 = *reinterpret_cast<const float4*>(&Af[(size_t)m*128 + (j-8)*8 + 4]);
            bf16* hp = reinterpret_cast<bf16*>(&v);
            hp[0]=f2b(f0.x); hp[1]=f2b(f0.y); hp[2]=f2b(f0.z); hp[3]=f2b(f0.w);
            hp[4]=f2b(f1.x); hp[5]=f2b(f1.y); hp[6]=f2b(f1.z); hp[7]=f2b(f1.w);
          }
        }
      }
      *reinterpret_cast<short8v*>(&sA[row][j*8]) = v;
    }
  }

  writeW(0);
  __syncthreads();

  short8v af[4][(NS>0)?NS:1];
  if constexpr(NW > 1){
    #pragma unroll
    for(int rt=0; rt<4; ++rt)
      #pragma unroll
      for(int s=0; s<NS; ++s)
        af[rt][s] = *reinterpret_cast<const short8v*>(&sA[wrow + rt*16 + l4][s*32 + lk8]);
  }

  #pragma unroll
  for(int w=0; w<NW; ++w){
    if(w+1 < NW) loadW(w+1);                 // issue early; consumed by writeW after compute

    f32x4 acc[4][2];
    #pragma unroll
    for(int rt=0; rt<4; ++rt){ acc[rt][0]=fzero; acc[rt][1]=fzero; }

    const short* wb = &sW[(NW>1)?(w&1):0][0][0];
    #pragma unroll
    for(int s=0; s<NS; ++s){
      short8v b0 = *reinterpret_cast<const short8v*>(wb + (size_t)(wcol +      l4)*Kp + s*32 + lk8);
      short8v b1 = *reinterpret_cast<const short8v*>(wb + (size_t)(wcol + 16 + l4)*Kp + s*32 + lk8);
      #pragma unroll
      for(int rt=0; rt<4; ++rt){
        short8v a = (NW>1) ? af[rt][s]
                  : *reinterpret_cast<const short8v*>(&sA[wrow + rt*16 + l4][s*32 + lk8]);
        acc[rt][0] = __builtin_amdgcn_mfma_f32_16x16x32_bf16(a, b0, acc[rt][0], 0,0,0);
        acc[rt][1] = __builtin_amdgcn_mfma_f32_16x16x32_bf16(a, b1, acc[rt][1], 0,0,0);
      }
    }

    if(w+1 < NW){ writeW((w+1)&1); __syncthreads(); }

    // ---- store (C/D: col = l&15, row = (l>>4)*4 + reg  [m89/m91-verified]) ----
    #pragma unroll
    for(int rt=0; rt<4; ++rt){
      #pragma unroll
      for(int r=0; r<4; ++r){
        int row = m0 + wrow + rt*16 + ((l>>4)<<2) + r;
        if(row < M){
          if constexpr(AMODE != 2){
            float sc = 1.f;
            if(NW>1 && w==1) sc = dis[row];  // P0s is the dis-scaled gather twin
            #pragma unroll
            for(int ct=0; ct<2; ++ct){
              float vv = acc[rt][ct][r] * sc;
              Ol[w][(size_t)row*64 + wcol + ct*16 + l4] = f2b(vv);
            }
          } else {                            // mix: cols 0..31 -> Zf (f32); 32..63 -> O0 bf16 *dis
            float dm = dis[row];
            #pragma unroll
            for(int ct=0; ct<2; ++ct){
              int col = wcol + ct*16 + l4;
              float vv = acc[rt][ct][r];
              if(col < 32) Zf[(size_t)row*32 + col] = vv;
              else         O0[(size_t)row*32 + (col-32)] = f2b(vv*dm);
            }
          }
        }
      }
    }
  }
}

// ---------------- sparse prop + Clenshaw combine ----------------
// MODE 0: r = Z - 2a                         -> store SCALED (dis[v]*r)
// MODE 1: r = Z - 2a - BsubS*dinv            -> store SCALED
// MODE 2: r = relu(Z - a - BsubS*dinv + bias) + Zs + bias2 -> store normal bf16
// MODE 3: r = Z - a + bias                   -> store normal f32
template<int F, int MODE, typename ZT, typename OT>
__global__ __launch_bounds__(256) void k_prop(const int* __restrict__ row_ptr, const int* __restrict__ csr_src,
    const float* __restrict__ dis, const float* __restrict__ dinv, const bf16* __restrict__ BinS,
    const ZT* __restrict__ Z, const bf16* __restrict__ BsubS,
    const float* __restrict__ bias, const bf16* __restrict__ Zs, const float* __restrict__ bias2,
    OT* __restrict__ out, int N){
  constexpr int L   = F/2;          // lanes per node (feature pairs)
  constexpr int NPB = 256/L;        // nodes per block
  int v = blockIdx.x*NPB + threadIdx.x/L;
  if(v>=N) return;
  int f2 = threadIdx.x % L;
  const uint32_t* __restrict__ B32 = reinterpret_cast<const uint32_t*>(BinS);
  int e0=row_ptr[v], e1=row_ptr[v+1];
  unsigned idx32 = (unsigned)v*L + f2;

  // issue epilogue loads early — independent of gathers, latency overlaps
  float zL, zH; ld2(Z, idx32, zL, zH);
  float bsL=0.f, bsH=0.f;
  if constexpr(MODE==1 || MODE==2){
    uint32_t bu = reinterpret_cast<const uint32_t*>(BsubS)[idx32]; bsL=bl(bu); bsH=bh(bu);
  }
  float biL=0.f, biH=0.f;
  if constexpr(MODE>=2){
    float2 bv = reinterpret_cast<const float2*>(bias)[f2]; biL=bv.x; biH=bv.y;
  }
  float zsL=0.f, zsH=0.f, b2L=0.f, b2H=0.f;
  if constexpr(MODE==2){
    uint32_t su = reinterpret_cast<const uint32_t*>(Zs)[idx32]; zsL=bl(su); zsH=bh(su);
    float2 b2v = reinterpret_cast<const float2*>(bias2)[f2]; b2L=b2v.x; b2H=b2v.y;
  }
  float dv = dis[v];
  float di = dinv[v];

  float aL=0.f, aH=0.f;
  int e=e0;
  // main: L edges per iteration, ONE coalesced index load, distribute via shfl
  for(; e+L<=e1; e+=L){
    int si = csr_src[e + f2];
    #pragma unroll
    for(int c=0; c<L/16; ++c){
      int s[16];
      #pragma unroll
      for(int j=0;j<16;++j) s[j] = __shfl(si, c*16+j, L);
      uint32_t u[16];
      #pragma unroll
      for(int j=0;j<16;++j) u[j]=B32[(unsigned)s[j]*L + f2];
      #pragma unroll
      for(int j=0;j<16;++j){ aL+=bl(u[j]); aH+=bh(u[j]); }
    }
  }
  // remainder (< L edges): broadcast-load path
  if(e+16<=e1){
    int s[16];
    #pragma unroll
    for(int j=0;j<16;++j) s[j]=csr_src[e+j];
    uint32_t u[16];
    #pragma unroll
    for(int j=0;j<16;++j) u[j]=B32[(unsigned)s[j]*L + f2];
    #pragma unroll
    for(int j=0;j<16;++j){ aL+=bl(u[j]); aH+=bh(u[j]); }
    e+=16;
  }
  if(e+8<=e1){
    int s[8];
    #pragma unroll
    for(int j=0;j<8;++j) s[j]=csr_src[e+j];
    uint32_t u[8];
    #pragma unroll
    for(int j=0;j<8;++j) u[j]=B32[(unsigned)s[j]*L + f2];
    #pragma unroll
    for(int j=0;j<8;++j){ aL+=bl(u[j]); aH+=bh(u[j]); }
    e+=8;
  }
  if(e<e1){
    #pragma unroll
    for(int j=0;j<8;++j){
      int idx=e+j;
      int s=csr_src[idx<e1 ? idx : e0];
      uint32_t uu=B32[(unsigned)s*L + f2];
      if(idx<e1){ aL+=bl(uu); aH+=bh(uu); }
    }
  }
  aL*=dv; aH*=dv;                 // a = dis[v] * sum (BinS pre-scaled by dis[src])
  float rL, rH;
  if constexpr(MODE==0){ rL = zL - 2.f*aL;              rH = zH - 2.f*aH; }
  else if constexpr(MODE==1){ rL = zL - 2.f*aL - bsL*di; rH = zH - 2.f*aH - bsH*di; }
  else if constexpr(MODE==2){
    float tL = zL - aL - bsL*di + biL;
    float tH = zH - aH - bsH*di + biH;
    rL = fmaxf(tL,0.f) + zsL + b2L;
    rH = fmaxf(tH,0.f) + zsH + b2H;
  } else { rL = zL - aL + biL; rH = zH - aH + biH; }
  if constexpr(MODE<=1) st2(out, idx32, dv*rL, dv*rH);   // scaled store (single stream)
  else                  st2(out, idx32, rL, rH);
}

// ---------------- host ----------------

extern "C" void kernel_launch(void* const* d_in, const int* in_sizes, int n_in,
                              void* d_out, int out_size, void* d_ws, size_t ws_size,
                              hipStream_t stream) {
  const int N = in_sizes[0]/128;     // 100000
  const int E = in_sizes[1]/2;       // 3200000

  const float* x    = (const float*)d_in[0];
  const int*   ei   = (const int*  )d_in[1];
  const float* W0   = (const float*)d_in[2];
  const float* b0   = (const float*)d_in[3];
  const float* Ws0  = (const float*)d_in[4];
  const float* bs0  = (const float*)d_in[5];
  const float* W1   = (const float*)d_in[6];
  const float* b1   = (const float*)d_in[7];
  const float* Ws1  = (const float*)d_in[8];
  const float* bs1  = (const float*)d_in[9];
  const float* W2   = (const float*)d_in[10];
  const float* b2   = (const float*)d_in[11];
  const float* Ws2  = (const float*)d_in[12];
  const float* bs2  = (const float*)d_in[13];
  const float* Wmix = (const float*)d_in[14];
  const float* bmix = (const float*)d_in[15];
  float* out = (float*)d_out;

  const int* src = ei;
  const int* dst = ei + E;

  size_t off=0;
  char* ws=(char*)d_ws;
  auto alloc=[&](size_t bytes)->void*{ void* p = ws+off; off=(off+bytes+255)&~(size_t)255; return p; };
  int*   csr_src = (int*)  alloc((size_t)E*4);
  int*   row_ptr = (int*)  alloc((size_t)(N+1)*4);
  int*   deg     = (int*)  alloc((size_t)N*4);
  float* dis     = (float*)alloc((size_t)N*4);
  float* dinv    = (float*)alloc((size_t)N*4);
  int*   bsums   = (int*)  alloc(2048);
  int*   boffs   = (int*)  alloc(2048);
  bf16*  Z0      = (bf16*) alloc((size_t)N*64*2);
  bf16*  Z1      = (bf16*) alloc((size_t)N*64*2);  // reused as f32 N*32 for mix Z0
  bf16*  Z2      = (bf16*) alloc((size_t)N*64*2);
  bf16*  Z3      = (bf16*) alloc((size_t)N*64*2);
  bf16*  Z4      = (bf16*) alloc((size_t)N*64*2);
  bf16*  Zsb     = (bf16*) alloc((size_t)N*64*2);
  bf16*  P0s     = (bf16*) alloc((size_t)N*64*2);
  bf16*  P1s     = (bf16*) alloc((size_t)N*64*2);
  bf16*  P2s     = (bf16*) alloc((size_t)N*64*2);
  bf16*  hA      = (bf16*) alloc((size_t)N*64*2);
  bf16*  hB      = (bf16*) alloc((size_t)N*64*2);
  bf16*  WT0     = (bf16*) alloc((size_t)7*64*136*2);   // layer0 weights, transposed+padded bf16
  bf16*  WT1     = (bf16*) alloc((size_t)7*64*72*2);
  bf16*  WT2     = (bf16*) alloc((size_t)7*64*72*2);
  bf16*  WTm     = (bf16*) alloc((size_t)64*200*2);
  if(off > ws_size){
    fprintf(stderr, "kernel_launch: workspace too small: need %zu, have %zu\n", off, ws_size);
    return;
  }

  const int NB   = (N+255)/256;
  const int gE   = (E+255)/256;
  const int gM   = (N+127)/128;
  const int gP64 = (N+7)/8;      // k_prop<64>: 32 lanes/node, 8 nodes/block
  const int gP32 = (N+15)/16;    // k_prop<32>: 16 lanes/node, 16 nodes/block

  // bucketed-fill scratch: overlays Z0..Z2 (written only before first GEMM output)
  const int nbuk = (N+63)>>6;
  const int NB2  = (nbuk+255)/256;
  const int epc  = (E+255)/256;
  const bool fast_fill = (nbuk <= 1600);
  char*  gs         = (char*)Z0;
  uint2* ebuf       = (uint2*)gs;
  int*   chunk_hist = (int*)(gs + (((size_t)E*8 + 255) & ~(size_t)255));
  int*   binc       = chunk_hist + (size_t)nbuk*256;
  int*   btot       = binc + nbuk;
  int*   bbase      = btot + nbuk;

  // weight prep (independent of graph data)
  k_prep<<<496,256,0,stream>>>(W0,Ws0,W1,Ws1,W2,Ws2,Wmix, WT0,WT1,WT2,WTm);

  // graph prep (fast path: ZERO global atomics)
  if(fast_fill){
    hipMemsetAsync(btot, 0, (size_t)nbuk*4, stream);
    k_hist<<<256,256,0,stream>>>(dst, chunk_hist, btot, E, nbuk, epc);
    k_scan1<<<NB2,256,0,stream>>>(btot, binc, bsums, nbuk);
    k_scan2<<<1,512,0,stream>>>(bsums, boffs, NB2);
    k_bfix<<<NB2,256,0,stream>>>(binc, btot, boffs, bbase, nbuk);
    k_cscan<<<nbuk,256,0,stream>>>(chunk_hist, bbase, nbuk);
    k_bscat<<<256,256,0,stream>>>(src, dst, chunk_hist, ebuf, E, nbuk, epc);
    k_degf<<<nbuk,256,0,stream>>>(ebuf, bbase, btot, deg, N);
    k_scan1<<<NB,256,0,stream>>>(deg, row_ptr+1, bsums, N);
    k_scan2<<<1,512,0,stream>>>(bsums, boffs, NB);
    k_scan3<<<NB,256,0,stream>>>(row_ptr, boffs, deg, dis, dinv, N);
    k_fill3<<<nbuk,256,0,stream>>>(ebuf, bbase, btot, row_ptr, csr_src, N);
  } else {
    hipMemsetAsync(deg, 0, (size_t)N*4, stream);
    k_count<<<gE,256,0,stream>>>(dst, deg, E);
    k_scan1<<<NB,256,0,stream>>>(deg, row_ptr+1, bsums, N);
    k_scan2<<<1,512,0,stream>>>(bsums, boffs, NB);
    k_scan3<<<NB,256,0,stream>>>(row_ptr, boffs, deg, dis, dinv, N);
    k_fill<<<gE,256,0,stream>>>(src, dst, row_ptr, deg, csr_src, E);
  }

  auto PROPS=[&](const float* b, const float* bs_, bf16* hout){
    k_prop<64,0,bf16,bf16><<<gP64,256,0,stream>>>(row_ptr,csr_src,dis,dinv,P0s,Z4,nullptr,nullptr,nullptr,nullptr,P1s,N); // B4
    k_prop<64,1,bf16,bf16><<<gP64,256,0,stream>>>(row_ptr,csr_src,dis,dinv,P1s,Z3,P0s,nullptr,nullptr,nullptr,P2s,N);     // B3
    k_prop<64,1,bf16,bf16><<<gP64,256,0,stream>>>(row_ptr,csr_src,dis,dinv,P2s,Z2,P1s,nullptr,nullptr,nullptr,P0s,N);     // B2
    k_prop<64,1,bf16,bf16><<<gP64,256,0,stream>>>(row_ptr,csr_src,dis,dinv,P0s,Z1,P2s,nullptr,nullptr,nullptr,P1s,N);     // B1
    k_prop<64,2,bf16,bf16><<<gP64,256,0,stream>>>(row_ptr,csr_src,dis,dinv,P1s,Z0,P0s,b,Zsb,bs_,hout,N);                  // h'
  };

  // layer 0: A = x (f32, cvt on the fly), K=128
  k_mfma<128,7,1><<<gM,256,0,stream>>>(nullptr, x, WT0, Zsb,P0s,Z4,Z3,Z2,Z1,Z0, nullptr, dis, N);
  PROPS(b0, bs0, hA);
  // layer 1: A = hA bf16, K=64
  k_mfma<64,7,0><<<gM,256,0,stream>>>(hA, nullptr, WT1, Zsb,P0s,Z4,Z3,Z2,Z1,Z0, nullptr, dis, N);
  PROPS(b1, bs1, hB);
  // layer 2
  k_mfma<64,7,0><<<gM,256,0,stream>>>(hB, nullptr, WT2, Zsb,P0s,Z4,Z3,Z2,Z1,Z0, nullptr, dis, N);
  PROPS(b2, bs2, hA);

  // mix head: A = [hA | x] (K=192); cols 0..31 -> Zmixf (f32), cols 32..63 -> P0s (bf16, *dis)
  float* Zmixf = (float*)Z1;   // Z1 free after layer-2 props
  k_mfma<192,1,2><<<gM,256,0,stream>>>(hA, x, WTm, P0s,nullptr,nullptr,nullptr,nullptr,nullptr,nullptr, Zmixf, dis, N);
  k_prop<32,3,float,float><<<gP32,256,0,stream>>>(row_ptr,csr_src,dis,dinv,P0s,Zmixf,nullptr,bmix,nullptr,nullptr,out,N);
}

// Round 11
// 1331.918 us; speedup vs baseline: 1.1984x; 1.0365x over previous
//
#include <hip/hip_runtime.h>
#include <hip/hip_bf16.h>
#include <cstdio>
#include <cstdint>

typedef __hip_bfloat16 bf16;
typedef __attribute__((ext_vector_type(8)))  short short8v;  // 8 bf16 = 4 VGPR (MFMA A/B frag)
typedef __attribute__((ext_vector_type(4)))  float f32x4;    // MFMA C/D frag

static __device__ __forceinline__ float b2f(bf16 v){ return __bfloat162float(v); }
static __device__ __forceinline__ bf16  f2b(float v){ return __float2bfloat16(v); }
static __device__ __forceinline__ float ldf(const float* p){ return *p; }
static __device__ __forceinline__ float ldf(const bf16* p){ return b2f(*p); }

// bf16-pair helpers: u32 = [hi:lo] two consecutive bf16; bf16->f32 is exact bit-shift
static __device__ __forceinline__ float bl(uint32_t u){ union{uint32_t i; float f;} c; c.i = u<<16;          return c.f; }
static __device__ __forceinline__ float bh(uint32_t u){ union{uint32_t i; float f;} c; c.i = u & 0xffff0000u; return c.f; }
static __device__ __forceinline__ uint32_t pk(float lo, float hi){
  bf16 a=f2b(lo), b=f2b(hi);
  uint16_t ai=*reinterpret_cast<uint16_t*>(&a), bi=*reinterpret_cast<uint16_t*>(&b);
  return ((uint32_t)bi<<16) | ai;
}
// 8-feature (uint4 of bf16-pairs) unpack / accumulate / pack
static __device__ __forceinline__ void unp8(uint4 u, float* o){
  o[0]=bl(u.x); o[1]=bh(u.x); o[2]=bl(u.y); o[3]=bh(u.y);
  o[4]=bl(u.z); o[5]=bh(u.z); o[6]=bl(u.w); o[7]=bh(u.w);
}
static __device__ __forceinline__ void add8(uint4 u, float* a){
  a[0]+=bl(u.x); a[1]+=bh(u.x); a[2]+=bl(u.y); a[3]+=bh(u.y);
  a[4]+=bl(u.z); a[5]+=bh(u.z); a[6]+=bl(u.w); a[7]+=bh(u.w);
}
static __device__ __forceinline__ uint4 pk4(const float* r){
  return make_uint4(pk(r[0],r[1]), pk(r[2],r[3]), pk(r[4],r[5]), pk(r[6],r[7]));
}

// ---------------- graph prep ----------------
// [measured r5/r6]: 3.2M random global atomics cost ~128-162us each kernel and ~31B HBM
// write per atomic. Fast path: ZERO global atomics (bucket-sort + LDS cursors). [r8: verified,
// graph prep no longer in top-5]

// legacy pair (fallback when nbuk>1600)
__global__ void k_count(const int* __restrict__ dst, int* __restrict__ deg, int E){
  int e = blockIdx.x*256 + threadIdx.x;
  if(e<E) atomicAdd(&deg[dst[e]], 1);
}
__global__ void k_fill(const int* __restrict__ src, const int* __restrict__ dst,
                       const int* __restrict__ row_ptr, int* __restrict__ deg,
                       int* __restrict__ csr_src, int E){
  int e = blockIdx.x*256+threadIdx.x;
  if(e<E){
    int d = dst[e];
    int pos = row_ptr[d] + atomicAdd(&deg[d],-1) - 1;
    csr_src[pos] = src[e];
  }
}

__global__ void k_scan1(const int* __restrict__ deg, int* __restrict__ rp1, int* __restrict__ bsums, int N){
  __shared__ int s[256];
  int i = blockIdx.x*256 + threadIdx.x;
  int v = (i<N)? deg[i] : 0;
  s[threadIdx.x]=v; __syncthreads();
  for(int off=1; off<256; off<<=1){
    int t = (threadIdx.x>=off)? s[threadIdx.x-off] : 0;
    __syncthreads();
    s[threadIdx.x]+=t;
    __syncthreads();
  }
  if(i<N) rp1[i]=s[threadIdx.x];
  if(threadIdx.x==255) bsums[blockIdx.x]=s[255];
}

__global__ void k_scan2(const int* __restrict__ bsums, int* __restrict__ boffs, int NB){
  __shared__ int s[512];
  int x=threadIdx.x;
  int v = (x<NB)? bsums[x] : 0;
  s[x]=v; __syncthreads();
  for(int off=1; off<512; off<<=1){
    int t=(x>=off)? s[x-off]:0; __syncthreads();
    s[x]+=t; __syncthreads();
  }
  if(x<NB) boffs[x]=s[x]-v;  // exclusive prefix
}

__global__ void k_scan3(int* __restrict__ row_ptr, const int* __restrict__ boffs,
                        const int* __restrict__ deg, float* __restrict__ dis, float* __restrict__ dinv, int N){
  int i = blockIdx.x*256+threadIdx.x;
  if(i<N){
    row_ptr[i+1] += boffs[blockIdx.x];
    int d = deg[i];
    dis[i]  = (d>0)? rsqrtf((float)d) : 0.f;
    dinv[i] = (d>0)? sqrtf((float)d)  : 0.f;
    if(i==0) row_ptr[0]=0;
  }
}

// buckets = dst>>6 (64 nodes each); 256 edge-chunks; per-(bucket,chunk) exclusive regions
__global__ void k_hist(const int* __restrict__ dst, int* __restrict__ chunk_hist,
                       int* __restrict__ btot, int E, int nbuk, int epc){
  __shared__ int h[1600];
  for(int i=threadIdx.x;i<nbuk;i+=256) h[i]=0;
  __syncthreads();
  int base=blockIdx.x*epc, end=min(base+epc,E);
  for(int e=base+(int)threadIdx.x; e<end; e+=256) atomicAdd(&h[dst[e]>>6],1);
  __syncthreads();
  for(int i=threadIdx.x;i<nbuk;i+=256){
    int hv=h[i];
    chunk_hist[(size_t)i*256 + blockIdx.x]=hv;     // bucket-major [nbuk][256]
    if(hv) atomicAdd(&btot[i],hv);
  }
}

// bbase[i] = global exclusive prefix of btot  (binc = k_scan1 inclusive, boffs = block offsets)
__global__ void k_bfix(const int* __restrict__ binc, const int* __restrict__ btot,
                       const int* __restrict__ boffs, int* __restrict__ bbase, int nbuk){
  int i=blockIdx.x*256+threadIdx.x;
  if(i<nbuk) bbase[i] = binc[i] + boffs[i>>8] - btot[i];
}

// in-place: chunk_hist[i][c] -> bbase[i] + sum_{c'<c} chunk_hist[i][c']
__global__ void k_cscan(int* __restrict__ chunk_hist, const int* __restrict__ bbase, int nbuk){
  __shared__ int s[256];
  int b=blockIdx.x; if(b>=nbuk) return;
  int x=threadIdx.x;
  int v=chunk_hist[(size_t)b*256+x];
  s[x]=v; __syncthreads();
  for(int off=1; off<256; off<<=1){
    int t=(x>=off)? s[x-off]:0; __syncthreads();
    s[x]+=t; __syncthreads();
  }
  chunk_hist[(size_t)b*256+x] = s[x]-v + bbase[b];
}

__global__ void k_bscat(const int* __restrict__ src, const int* __restrict__ dst,
                        const int* __restrict__ cbase, uint2* __restrict__ ebuf,
                        int E, int nbuk, int epc){
  __shared__ int cur[1600];
  for(int i=threadIdx.x;i<nbuk;i+=256) cur[i]=cbase[(size_t)i*256 + blockIdx.x];
  __syncthreads();
  int base=blockIdx.x*epc, end=min(base+epc,E);
  for(int e=base+(int)threadIdx.x; e<end; e+=256){
    int d=dst[e], s=src[e];
    int p=atomicAdd(&cur[d>>6],1);                 // LDS atomic, chunk-private region
    ebuf[p]=make_uint2((unsigned)s,(unsigned)d);
  }
}

// deg via per-bucket LDS histogram over the bucket's contiguous edge slice (no global atomics)
__global__ void k_degf(const uint2* __restrict__ ebuf, const int* __restrict__ bbase,
                       const int* __restrict__ btot, int* __restrict__ deg, int N){
  __shared__ int cnt[64];
  int b=blockIdx.x;
  if(threadIdx.x<64) cnt[threadIdx.x]=0;
  __syncthreads();
  int e0=bbase[b], e1=e0+btot[b];
  for(int e=e0+(int)threadIdx.x; e<e1; e+=256) atomicAdd(&cnt[ebuf[e].y & 63],1);
  __syncthreads();
  int n=b*64+(int)threadIdx.x;
  if(threadIdx.x<64 && n<N) deg[n]=cnt[threadIdx.x];
}

// CSR fill via per-bucket LDS cursors (no global atomics)
__global__ void k_fill3(const uint2* __restrict__ ebuf, const int* __restrict__ bbase,
                        const int* __restrict__ btot, const int* __restrict__ row_ptr,
                        int* __restrict__ csr_src, int N){
  __shared__ int cur[64];
  __shared__ int rp[64];
  int b=blockIdx.x;
  int n=b*64+(int)threadIdx.x;
  if(threadIdx.x<64){
    cur[threadIdx.x]=0;
    rp[threadIdx.x] = (n<N)? row_ptr[n] : 0;
  }
  __syncthreads();
  int e0=bbase[b], e1=e0+btot[b];
  for(int e=e0+(int)threadIdx.x; e<e1; e+=256){
    uint2 p=ebuf[e];
    int li=(int)(p.y & 63);
    int idx=atomicAdd(&cur[li],1);                 // LDS atomic
    csr_src[rp[li]+idx]=(int)p.x;
  }
}

// -------- weight prep: f32 [K][64] -> bf16 WT [64][Kp] (transposed, padded) --------
__global__ void k_prep(const float* __restrict__ W0, const float* __restrict__ Ws0,
                       const float* __restrict__ W1, const float* __restrict__ Ws1,
                       const float* __restrict__ W2, const float* __restrict__ Ws2,
                       const float* __restrict__ Wmix,
                       bf16* __restrict__ WT0, bf16* __restrict__ WT1,
                       bf16* __restrict__ WT2, bf16* __restrict__ WTm){
  int idx = blockIdx.x*256 + threadIdx.x;
  if(idx < 57344){                                   // layer0, K=128, Kp=136
    int w = idx >> 13, r = idx & 8191;
    int k = r >> 6, n = r & 63;
    float v = (w==0)? Ws0[(k<<6)+n] : W0[(((6-w)<<7) + k)*64 + n];
    WT0[(size_t)((w<<6)+n)*136 + k] = f2b(v);
  } else if(idx < 57344+28672){                      // layer1, K=64, Kp=72
    int i2 = idx - 57344;
    int w = i2 >> 12, r = i2 & 4095;
    int k = r >> 6, n = r & 63;
    float v = (w==0)? Ws1[(k<<6)+n] : W1[(((6-w)<<6) + k)*64 + n];
    WT1[(size_t)((w<<6)+n)*72 + k] = f2b(v);
  } else if(idx < 57344+2*28672){                    // layer2
    int i2 = idx - (57344+28672);
    int w = i2 >> 12, r = i2 & 4095;
    int k = r >> 6, n = r & 63;
    float v = (w==0)? Ws2[(k<<6)+n] : W2[(((6-w)<<6) + k)*64 + n];
    WT2[(size_t)((w<<6)+n)*72 + k] = f2b(v);
  } else if(idx < 57344+2*28672+12288){              // mix, K=192, Kp=200
    int i2 = idx - (57344+2*28672);
    int n = i2 / 192, k = i2 % 192;
    float v = (n<32)? Wmix[k*32 + n] : Wmix[6144 + k*32 + (n-32)];
    WTm[(size_t)n*200 + k] = f2b(v);
  }
}

// -------- MFMA mega-GEMM: BM=128, 4 waves (2x2), wave-tile 64x32, 16x16x32 bf16 --------
template<int K, int NW, int AMODE>
__global__ __launch_bounds__(256,2) void k_mfma(
    const bf16* __restrict__ Ab, const float* __restrict__ Af, const bf16* __restrict__ WT,
    bf16* __restrict__ O0, bf16* __restrict__ O1, bf16* __restrict__ O2, bf16* __restrict__ O3,
    bf16* __restrict__ O4, bf16* __restrict__ O5, bf16* __restrict__ O6,
    float* __restrict__ Zf, const float* __restrict__ dis, int M)
{
  constexpr int Kp = K + 8;
  static_assert(Kp % 8 == 0, "Kp must keep 16B alignment");
  constexpr int NS = K / 32;                 // K-slices per MFMA chain
  constexpr int NSLOT = (NW>1) ? 2 : 1;
  __shared__ short sA[128][Kp];
  __shared__ short sW[NSLOT][64][Kp];

  const int t    = threadIdx.x;
  const int m0   = blockIdx.x * 128;
  const int l    = t & 63;
  const int wid  = t >> 6;
  const int wrow = (wid >> 1) * 64;          // wave row base in tile
  const int wcol = (wid & 1) * 32;           // wave col base
  const int l4   = l & 15;
  const int lk8  = (l >> 4) * 8;             // contiguous-8 k sub-offset (m97-verified layout)

  bf16* const Ol[7] = {O0,O1,O2,O3,O4,O5,O6};
  const short8v szero = {0,0,0,0,0,0,0,0};
  const f32x4   fzero = {0.f,0.f,0.f,0.f};

  constexpr int WCH = (64*Kp)/8;             // 16B chunks per W tile
  constexpr int WIT = (WCH + 255)/256;
  short8v wreg[WIT];
  auto loadW = [&](int w){
    #pragma unroll
    for(int it=0; it<WIT; ++it){
      int c = t + it*256;
      if(c < WCH) wreg[it] = *reinterpret_cast<const short8v*>(&WT[(size_t)w*(64*Kp) + (size_t)c*8]);
    }
  };
  auto writeW = [&](int slot){
    short* base = &sW[slot][0][0];
    #pragma unroll
    for(int it=0; it<WIT; ++it){
      int c = t + it*256;
      if(c < WCH) *reinterpret_cast<short8v*>(base + (size_t)c*8) = wreg[it];
    }
  };

  loadW(0);   // global loads in flight while we stage A

  {
    constexpr int CPR = K/8;                 // 16B chunks per row
    #pragma unroll
    for(int it=0; it<(128*CPR)/256; ++it){
      int c = t + it*256;
      int row = c / CPR, j = c % CPR;
      int m = m0 + row;
      short8v v = szero;
      if(m < M){
        if constexpr(AMODE==0){
          v = *reinterpret_cast<const short8v*>(&Ab[(size_t)m*K + j*8]);
        } else if constexpr(AMODE==1){
          float4 f0 = *reinterpret_cast<const float4*>(&Af[(size_t)m*K + j*8]);
          float4 f1 = *reinterpret_cast<const float4*>(&Af[(size_t)m*K + j*8 + 4]);
          bf16* hp = reinterpret_cast<bf16*>(&v);
          hp[0]=f2b(f0.x); hp[1]=f2b(f0.y); hp[2]=f2b(f0.z); hp[3]=f2b(f0.w);
          hp[4]=f2b(f1.x); hp[5]=f2b(f1.y); hp[6]=f2b(f1.z); hp[7]=f2b(f1.w);
        } else {                             // mix: j<8 -> hA (64 bf16), else x (128 f32)
          if(j < 8){
            v = *reinterpret_cast<const short8v*>(&Ab[(size_t)m*64 + j*8]);
          } else {
            float4 f0 = *reinterpret_cast<const float4*>(&Af[(size_t)m*128 + (j-8)*8]);
            float4 f1 = *reinterpret_cast<const float4*>(&Af[(size_t)m*128 + (j-8)*8 + 4]);
            bf16* hp = reinterpret_cast<bf16*>(&v);
            hp[0]=f2b(f0.x); hp[1]=f2b(f0.y); hp[2]=f2b(f0.z); hp[3]=f2b(f0.w);
            hp[4]=f2b(f1.x); hp[5]=f2b(f1.y); hp[6]=f2b(f1.z); hp[7]=f2b(f1.w);
          }
        }
      }
      *reinterpret_cast<short8v*>(&sA[row][j*8]) = v;
    }
  }

  writeW(0);
  __syncthreads();

  short8v af[4][(NS>0)?NS:1];
  if constexpr(NW > 1){
    #pragma unroll
    for(int rt=0; rt<4; ++rt)
      #pragma unroll
      for(int s=0; s<NS; ++s)
        af[rt][s] = *reinterpret_cast<const short8v*>(&sA[wrow + rt*16 + l4][s*32 + lk8]);
  }

  #pragma unroll
  for(int w=0; w<NW; ++w){
    if(w+1 < NW) loadW(w+1);                 // issue early; consumed by writeW after compute

    f32x4 acc[4][2];
    #pragma unroll
    for(int rt=0; rt<4; ++rt){ acc[rt][0]=fzero; acc[rt][1]=fzero; }

    const short* wb = &sW[(NW>1)?(w&1):0][0][0];
    #pragma unroll
    for(int s=0; s<NS; ++s){
      short8v b0 = *reinterpret_cast<const short8v*>(wb + (size_t)(wcol +      l4)*Kp + s*32 + lk8);
      short8v b1 = *reinterpret_cast<const short8v*>(wb + (size_t)(wcol + 16 + l4)*Kp + s*32 + lk8);
      #pragma unroll
      for(int rt=0; rt<4; ++rt){
        short8v a = (NW>1) ? af[rt][s]
                  : *reinterpret_cast<const short8v*>(&sA[wrow + rt*16 + l4][s*32 + lk8]);
        acc[rt][0] = __builtin_amdgcn_mfma_f32_16x16x32_bf16(a, b0, acc[rt][0], 0,0,0);
        acc[rt][1] = __builtin_amdgcn_mfma_f32_16x16x32_bf16(a, b1, acc[rt][1], 0,0,0);
      }
    }

    if(w+1 < NW){ writeW((w+1)&1); __syncthreads(); }

    // ---- store (C/D: col = l&15, row = (l>>4)*4 + reg  [m89/m91-verified]) ----
    #pragma unroll
    for(int rt=0; rt<4; ++rt){
      #pragma unroll
      for(int r=0; r<4; ++r){
        int row = m0 + wrow + rt*16 + ((l>>4)<<2) + r;
        if(row < M){
          if constexpr(AMODE != 2){
            float sc = 1.f;
            if(NW>1 && w==1) sc = dis[row];  // P0s is the dis-scaled gather twin
            #pragma unroll
            for(int ct=0; ct<2; ++ct){
              float vv = acc[rt][ct][r] * sc;
              Ol[w][(size_t)row*64 + wcol + ct*16 + l4] = f2b(vv);
            }
          } else {                            // mix: cols 0..31 -> Zf (f32); 32..63 -> O0 bf16 *dis
            float dm = dis[row];
            #pragma unroll
            for(int ct=0; ct<2; ++ct){
              int col = wcol + ct*16 + l4;
              float vv = acc[rt][ct][r];
              if(col < 32) Zf[(size_t)row*32 + col] = vv;
              else         O0[(size_t)row*32 + (col-32)] = f2b(vv*dm);
            }
          }
        }
      }
    }
  }
}

// ---------------- sparse prop + Clenshaw combine ----------------
// [r8 measured: 78.7us/hop, FETCH 176MB, hbm 39%, VALU 37%, L2-read 15% -> nothing
// saturated = issue/latency-bound.] r9 restructure: 8 lanes/node, uint4 gathers (each
// lane owns 8 features = 16B of the 128B row). Wave covers 8 nodes -> 4x fewer wave-wide
// VMEM+DS instrs per edge, 4x more independent gather streams. Math bit-identical.
// MODE 0: r = Z - 2a                         -> store SCALED (dis[v]*r)
// MODE 1: r = Z - 2a - BsubS*dinv            -> store SCALED
// MODE 2: r = relu(Z - a - BsubS*dinv + bias) + Zs + bias2 -> store normal bf16
// MODE 3: r = Z - a + bias                   -> store normal f32
template<int F, int MODE, typename ZT, typename OT>
__global__ __launch_bounds__(256) void k_prop(const int* __restrict__ row_ptr, const int* __restrict__ csr_src,
    const float* __restrict__ dis, const float* __restrict__ dinv, const bf16* __restrict__ BinS,
    const ZT* __restrict__ Z, const bf16* __restrict__ BsubS,
    const float* __restrict__ bias, const bf16* __restrict__ Zs, const float* __restrict__ bias2,
    OT* __restrict__ out, int N){
  constexpr int L   = F/8;          // lanes per node; lane owns 8 features (1 uint4 of bf16-pairs)
  constexpr int NPB = 256/L;        // nodes per block
  int v = blockIdx.x*NPB + threadIdx.x/L;
  if(v>=N) return;
  int fl = threadIdx.x % L;
  const uint4* __restrict__ B4 = reinterpret_cast<const uint4*>(BinS);
  int e0=row_ptr[v], e1=row_ptr[v+1];
  unsigned q = (unsigned)v*L + fl;  // uint4 index into N x F bf16 streams

  // epilogue operands early (latency overlaps the gather chain)
  float z[8];
  if constexpr(MODE==3){
    const float* zp = reinterpret_cast<const float*>(Z) + (size_t)v*F + fl*8;
    float4 a=*reinterpret_cast<const float4*>(zp), b=*reinterpret_cast<const float4*>(zp+4);
    z[0]=a.x; z[1]=a.y; z[2]=a.z; z[3]=a.w; z[4]=b.x; z[5]=b.y; z[6]=b.z; z[7]=b.w;
  } else {
    unp8(reinterpret_cast<const uint4*>(Z)[q], z);
  }
  float bs[8]={};
  if constexpr(MODE==1 || MODE==2) unp8(reinterpret_cast<const uint4*>(BsubS)[q], bs);
  float bi[8]={};
  if constexpr(MODE>=2){
    float4 a=*reinterpret_cast<const float4*>(bias + fl*8);
    float4 b=*reinterpret_cast<const float4*>(bias + fl*8 + 4);
    bi[0]=a.x; bi[1]=a.y; bi[2]=a.z; bi[3]=a.w; bi[4]=b.x; bi[5]=b.y; bi[6]=b.z; bi[7]=b.w;
  }
  float zs[8]={}, b2[8]={};
  if constexpr(MODE==2){
    unp8(reinterpret_cast<const uint4*>(Zs)[q], zs);
    float4 a=*reinterpret_cast<const float4*>(bias2 + fl*8);
    float4 b=*reinterpret_cast<const float4*>(bias2 + fl*8 + 4);
    b2[0]=a.x; b2[1]=a.y; b2[2]=a.z; b2[3]=a.w; b2[4]=b.x; b2[5]=b.y; b2[6]=b.z; b2[7]=b.w;
  }
  float dv = dis[v];
  float di = dinv[v];

  float acc[8]={};
  int e=e0;
  // paired chunks: both index loads issue upfront (one exposed latency per 2L edges)
  for(; e+2*L<=e1; e+=2*L){
    int si0 = csr_src[e + fl];
    int si1 = csr_src[e + L + fl];
    uint4 g0[L], g1[L];
    #pragma unroll
    for(int j=0;j<L;++j){ int s=__shfl(si0,j,L); g0[j]=B4[(size_t)s*L+fl]; }
    #pragma unroll
    for(int j=0;j<L;++j){ int s=__shfl(si1,j,L); g1[j]=B4[(size_t)s*L+fl]; }
    #pragma unroll
    for(int j=0;j<L;++j) add8(g0[j], acc);
    #pragma unroll
    for(int j=0;j<L;++j) add8(g1[j], acc);
  }
  if(e+L<=e1){
    int si = csr_src[e + fl];
    uint4 g[L];
    #pragma unroll
    for(int j=0;j<L;++j){ int s=__shfl(si,j,L); g[j]=B4[(size_t)s*L+fl]; }
    #pragma unroll
    for(int j=0;j<L;++j) add8(g[j], acc);
    e+=L;
  }
  if(e<e1){                          // tail: 1..L-1 edges, broadcast loads, predicated
    #pragma unroll
    for(int j=0;j<L-1;++j){
      int idx=e+j;
      int s=csr_src[idx<e1 ? idx : e0];
      uint4 g=B4[(size_t)s*L+fl];
      if(idx<e1) add8(g, acc);
    }
  }

  float r[8];
  #pragma unroll
  for(int i=0;i<8;++i){
    float a = dv*acc[i];            // a = dis[v] * sum (BinS pre-scaled by dis[src])
    if constexpr(MODE==0)      r[i] = z[i] - 2.f*a;
    else if constexpr(MODE==1) r[i] = z[i] - 2.f*a - bs[i]*di;
    else if constexpr(MODE==2){ float tv = z[i] - a - bs[i]*di + bi[i];
                                r[i] = fmaxf(tv,0.f) + zs[i] + b2[i]; }
    else                       r[i] = z[i] - a + bi[i];
    if constexpr(MODE<=1) r[i] *= dv;   // scaled store (single stream)
  }
  if constexpr(MODE==3){
    float* op = reinterpret_cast<float*>(out) + (size_t)v*F + fl*8;
    *reinterpret_cast<float4*>(op)   = make_float4(r[0],r[1],r[2],r[3]);
    *reinterpret_cast<float4*>(op+4) = make_float4(r[4],r[5],r[6],r[7]);
  } else {
    reinterpret_cast<uint4*>(out)[q] = pk4(r);
  }
}

// ---------------- host ----------------

extern "C" void kernel_launch(void* const* d_in, const int* in_sizes, int n_in,
                              void* d_out, int out_size, void* d_ws, size_t ws_size,
                              hipStream_t stream) {
  const int N = in_sizes[0]/128;     // 100000
  const int E = in_sizes[1]/2;       // 3200000

  const float* x    = (const float*)d_in[0];
  const int*   ei   = (const int*  )d_in[1];
  const float* W0   = (const float*)d_in[2];
  const float* b0   = (const float*)d_in[3];
  const float* Ws0  = (const float*)d_in[4];
  const float* bs0  = (const float*)d_in[5];
  const float* W1   = (const float*)d_in[6];
  const float* b1   = (const float*)d_in[7];
  const float* Ws1  = (const float*)d_in[8];
  const float* bs1  = (const float*)d_in[9];
  const float* W2   = (const float*)d_in[10];
  const float* b2   = (const float*)d_in[11];
  const float* Ws2  = (const float*)d_in[12];
  const float* bs2  = (const float*)d_in[13];
  const float* Wmix = (const float*)d_in[14];
  const float* bmix = (const float*)d_in[15];
  float* out = (float*)d_out;

  const int* src = ei;
  const int* dst = ei + E;

  size_t off=0;
  char* ws=(char*)d_ws;
  auto alloc=[&](size_t bytes)->void*{ void* p = ws+off; off=(off+bytes+255)&~(size_t)255; return p; };
  int*   csr_src = (int*)  alloc((size_t)E*4);
  int*   row_ptr = (int*)  alloc((size_t)(N+1)*4);
  int*   deg     = (int*)  alloc((size_t)N*4);
  float* dis     = (float*)alloc((size_t)N*4);
  float* dinv    = (float*)alloc((size_t)N*4);
  int*   bsums   = (int*)  alloc(2048);
  int*   boffs   = (int*)  alloc(2048);
  bf16*  Z0      = (bf16*) alloc((size_t)N*64*2);
  bf16*  Z1      = (bf16*) alloc((size_t)N*64*2);  // reused as f32 N*32 for mix Z0
  bf16*  Z2      = (bf16*) alloc((size_t)N*64*2);
  bf16*  Z3      = (bf16*) alloc((size_t)N*64*2);
  bf16*  Z4      = (bf16*) alloc((size_t)N*64*2);
  bf16*  Zsb     = (bf16*) alloc((size_t)N*64*2);
  bf16*  P0s     = (bf16*) alloc((size_t)N*64*2);
  bf16*  P1s     = (bf16*) alloc((size_t)N*64*2);
  bf16*  P2s     = (bf16*) alloc((size_t)N*64*2);
  bf16*  hA      = (bf16*) alloc((size_t)N*64*2);
  bf16*  hB      = (bf16*) alloc((size_t)N*64*2);
  bf16*  WT0     = (bf16*) alloc((size_t)7*64*136*2);   // layer0 weights, transposed+padded bf16
  bf16*  WT1     = (bf16*) alloc((size_t)7*64*72*2);
  bf16*  WT2     = (bf16*) alloc((size_t)7*64*72*2);
  bf16*  WTm     = (bf16*) alloc((size_t)64*200*2);
  if(off > ws_size){
    fprintf(stderr, "kernel_launch: workspace too small: need %zu, have %zu\n", off, ws_size);
    return;
  }

  const int NB   = (N+255)/256;
  const int gE   = (E+255)/256;
  const int gM   = (N+127)/128;
  const int gP64 = (N+31)/32;    // k_prop<64>: 8 lanes/node, 32 nodes/block
  const int gP32 = (N+63)/64;    // k_prop<32>: 4 lanes/node, 64 nodes/block

  // bucketed-fill scratch: overlays Z0..Z2 (written only before first GEMM output)
  const int nbuk = (N+63)>>6;
  const int NB2  = (nbuk+255)/256;
  const int epc  = (E+255)/256;
  const bool fast_fill = (nbuk <= 1600);
  char*  gs         = (char*)Z0;
  uint2* ebuf       = (uint2*)gs;
  int*   chunk_hist = (int*)(gs + (((size_t)E*8 + 255) & ~(size_t)255));
  int*   binc       = chunk_hist + (size_t)nbuk*256;
  int*   btot       = binc + nbuk;
  int*   bbase      = btot + nbuk;

  // weight prep (independent of graph data)
  k_prep<<<496,256,0,stream>>>(W0,Ws0,W1,Ws1,W2,Ws2,Wmix, WT0,WT1,WT2,WTm);

  // graph prep (fast path: ZERO global atomics)
  if(fast_fill){
    hipMemsetAsync(btot, 0, (size_t)nbuk*4, stream);
    k_hist<<<256,256,0,stream>>>(dst, chunk_hist, btot, E, nbuk, epc);
    k_scan1<<<NB2,256,0,stream>>>(btot, binc, bsums, nbuk);
    k_scan2<<<1,512,0,stream>>>(bsums, boffs, NB2);
    k_bfix<<<NB2,256,0,stream>>>(binc, btot, boffs, bbase, nbuk);
    k_cscan<<<nbuk,256,0,stream>>>(chunk_hist, bbase, nbuk);
    k_bscat<<<256,256,0,stream>>>(src, dst, chunk_hist, ebuf, E, nbuk, epc);
    k_degf<<<nbuk,256,0,stream>>>(ebuf, bbase, btot, deg, N);
    k_scan1<<<NB,256,0,stream>>>(deg, row_ptr+1, bsums, N);
    k_scan2<<<1,512,0,stream>>>(bsums, boffs, NB);
    k_scan3<<<NB,256,0,stream>>>(row_ptr, boffs, deg, dis, dinv, N);
    k_fill3<<<nbuk,256,0,stream>>>(ebuf, bbase, btot, row_ptr, csr_src, N);
  } else {
    hipMemsetAsync(deg, 0, (size_t)N*4, stream);
    k_count<<<gE,256,0,stream>>>(dst, deg, E);
    k_scan1<<<NB,256,0,stream>>>(deg, row_ptr+1, bsums, N);
    k_scan2<<<1,512,0,stream>>>(bsums, boffs, NB);
    k_scan3<<<NB,256,0,stream>>>(row_ptr, boffs, deg, dis, dinv, N);
    k_fill<<<gE,256,0,stream>>>(src, dst, row_ptr, deg, csr_src, E);
  }

  auto PROPS=[&](const float* b, const float* bs_, bf16* hout){
    k_prop<64,0,bf16,bf16><<<gP64,256,0,stream>>>(row_ptr,csr_src,dis,dinv,P0s,Z4,nullptr,nullptr,nullptr,nullptr,P1s,N); // B4
    k_prop<64,1,bf16,bf16><<<gP64,256,0,stream>>>(row_ptr,csr_src,dis,dinv,P1s,Z3,P0s,nullptr,nullptr,nullptr,P2s,N);     // B3
    k_prop<64,1,bf16,bf16><<<gP64,256,0,stream>>>(row_ptr,csr_src,dis,dinv,P2s,Z2,P1s,nullptr,nullptr,nullptr,P0s,N);     // B2
    k_prop<64,1,bf16,bf16><<<gP64,256,0,stream>>>(row_ptr,csr_src,dis,dinv,P0s,Z1,P2s,nullptr,nullptr,nullptr,P1s,N);     // B1
    k_prop<64,2,bf16,bf16><<<gP64,256,0,stream>>>(row_ptr,csr_src,dis,dinv,P1s,Z0,P0s,b,Zsb,bs_,hout,N);                  // h'
  };

  // layer 0: A = x (f32, cvt on the fly), K=128
  k_mfma<128,7,1><<<gM,256,0,stream>>>(nullptr, x, WT0, Zsb,P0s,Z4,Z3,Z2,Z1,Z0, nullptr, dis, N);
  PROPS(b0, bs0, hA);
  // layer 1: A = hA bf16, K=64
  k_mfma<64,7,0><<<gM,256,0,stream>>>(hA, nullptr, WT1, Zsb,P0s,Z4,Z3,Z2,Z1,Z0, nullptr, dis, N);
  PROPS(b1, bs1, hB);
  // layer 2
  k_mfma<64,7,0><<<gM,256,0,stream>>>(hB, nullptr, WT2, Zsb,P0s,Z4,Z3,Z2,Z1,Z0, nullptr, dis, N);
  PROPS(b2, bs2, hA);

  // mix head: A = [hA | x] (K=192); cols 0..31 -> Zmixf (f32), cols 32..63 -> P0s (bf16, *dis)
  float* Zmixf = (float*)Z1;   // Z1 free after layer-2 props
  k_mfma<192,1,2><<<gM,256,0,stream>>>(hA, x, WTm, P0s,nullptr,nullptr,nullptr,nullptr,nullptr,nullptr, Zmixf, dis, N);
  k_prop<32,3,float,float><<<gP32,256,0,stream>>>(row_ptr,csr_src,dis,dinv,P0s,Zmixf,nullptr,bmix,nullptr,nullptr,out,N);
}

// Round 12
// 1316.703 us; speedup vs baseline: 1.2123x; 1.0116x over previous
//
#include <hip/hip_runtime.h>
#include <hip/hip_bf16.h>
#include <cstdio>
#include <cstdint>

typedef __hip_bfloat16 bf16;
typedef __attribute__((ext_vector_type(8)))  short short8v;  // 8 bf16 = 4 VGPR (MFMA A/B frag)
typedef __attribute__((ext_vector_type(4)))  float f32x4;    // MFMA C/D frag

static __device__ __forceinline__ float b2f(bf16 v){ return __bfloat162float(v); }
static __device__ __forceinline__ bf16  f2b(float v){ return __float2bfloat16(v); }
static __device__ __forceinline__ float ldf(const float* p){ return *p; }
static __device__ __forceinline__ float ldf(const bf16* p){ return b2f(*p); }

// bf16-pair helpers: u32 = [hi:lo] two consecutive bf16; bf16->f32 is exact bit-shift
static __device__ __forceinline__ float bl(uint32_t u){ union{uint32_t i; float f;} c; c.i = u<<16;          return c.f; }
static __device__ __forceinline__ float bh(uint32_t u){ union{uint32_t i; float f;} c; c.i = u & 0xffff0000u; return c.f; }
static __device__ __forceinline__ uint32_t pk(float lo, float hi){
  bf16 a=f2b(lo), b=f2b(hi);
  uint16_t ai=*reinterpret_cast<uint16_t*>(&a), bi=*reinterpret_cast<uint16_t*>(&b);
  return ((uint32_t)bi<<16) | ai;
}
// 8-feature (uint4 of bf16-pairs) unpack / accumulate / pack
static __device__ __forceinline__ void unp8(uint4 u, float* o){
  o[0]=bl(u.x); o[1]=bh(u.x); o[2]=bl(u.y); o[3]=bh(u.y);
  o[4]=bl(u.z); o[5]=bh(u.z); o[6]=bl(u.w); o[7]=bh(u.w);
}
static __device__ __forceinline__ void add8(uint4 u, float* a){
  a[0]+=bl(u.x); a[1]+=bh(u.x); a[2]+=bl(u.y); a[3]+=bh(u.y);
  a[4]+=bl(u.z); a[5]+=bh(u.z); a[6]+=bl(u.w); a[7]+=bh(u.w);
}
static __device__ __forceinline__ uint4 pk4(const float* r){
  return make_uint4(pk(r[0],r[1]), pk(r[2],r[3]), pk(r[4],r[5]), pk(r[6],r[7]));
}

// ---------------- graph prep ----------------
// [measured r5/r6]: 3.2M random global atomics cost ~128-162us each kernel and ~31B HBM
// write per atomic. Fast path: ZERO global atomics (bucket-sort + LDS cursors).
// [r11 measured: k_bscat 70us @ 8.2% occupancy, VALU 1%, hbm 19% -> latency-starved
// (256 blocks = 4 waves/CU, 49 serial iters/thread). Fix: 1024-thread blocks -> 16 waves/CU.]

// legacy pair (fallback when nbuk>1600)
__global__ void k_count(const int* __restrict__ dst, int* __restrict__ deg, int E){
  int e = blockIdx.x*256 + threadIdx.x;
  if(e<E) atomicAdd(&deg[dst[e]], 1);
}
__global__ void k_fill(const int* __restrict__ src, const int* __restrict__ dst,
                       const int* __restrict__ row_ptr, int* __restrict__ deg,
                       int* __restrict__ csr_src, int E){
  int e = blockIdx.x*256+threadIdx.x;
  if(e<E){
    int d = dst[e];
    int pos = row_ptr[d] + atomicAdd(&deg[d],-1) - 1;
    csr_src[pos] = src[e];
  }
}

__global__ void k_scan1(const int* __restrict__ deg, int* __restrict__ rp1, int* __restrict__ bsums, int N){
  __shared__ int s[256];
  int i = blockIdx.x*256 + threadIdx.x;
  int v = (i<N)? deg[i] : 0;
  s[threadIdx.x]=v; __syncthreads();
  for(int off=1; off<256; off<<=1){
    int t = (threadIdx.x>=off)? s[threadIdx.x-off] : 0;
    __syncthreads();
    s[threadIdx.x]+=t;
    __syncthreads();
  }
  if(i<N) rp1[i]=s[threadIdx.x];
  if(threadIdx.x==255) bsums[blockIdx.x]=s[255];
}

__global__ void k_scan2(const int* __restrict__ bsums, int* __restrict__ boffs, int NB){
  __shared__ int s[512];
  int x=threadIdx.x;
  int v = (x<NB)? bsums[x] : 0;
  s[x]=v; __syncthreads();
  for(int off=1; off<512; off<<=1){
    int t=(x>=off)? s[x-off]:0; __syncthreads();
    s[x]+=t; __syncthreads();
  }
  if(x<NB) boffs[x]=s[x]-v;  // exclusive prefix
}

__global__ void k_scan3(int* __restrict__ row_ptr, const int* __restrict__ boffs,
                        const int* __restrict__ deg, float* __restrict__ dis, float* __restrict__ dinv, int N){
  int i = blockIdx.x*256+threadIdx.x;
  if(i<N){
    row_ptr[i+1] += boffs[blockIdx.x];
    int d = deg[i];
    dis[i]  = (d>0)? rsqrtf((float)d) : 0.f;
    dinv[i] = (d>0)? sqrtf((float)d)  : 0.f;
    if(i==0) row_ptr[0]=0;
  }
}

// buckets = dst>>6 (64 nodes each); 256 edge-chunks; per-(bucket,chunk) exclusive regions
// 1024 threads/block (r11 fix): 16 waves/CU, ~12 serial iters/thread
__global__ void k_hist(const int* __restrict__ dst, int* __restrict__ chunk_hist,
                       int* __restrict__ btot, int E, int nbuk, int epc){
  __shared__ int h[1600];
  for(int i=threadIdx.x;i<nbuk;i+=1024) h[i]=0;
  __syncthreads();
  int base=blockIdx.x*epc, end=min(base+epc,E);
  for(int e=base+(int)threadIdx.x; e<end; e+=1024) atomicAdd(&h[dst[e]>>6],1);
  __syncthreads();
  for(int i=threadIdx.x;i<nbuk;i+=1024){
    int hv=h[i];
    chunk_hist[(size_t)i*256 + blockIdx.x]=hv;     // bucket-major [nbuk][256]
    if(hv) atomicAdd(&btot[i],hv);
  }
}

// bbase[i] = global exclusive prefix of btot  (binc = k_scan1 inclusive, boffs = block offsets)
__global__ void k_bfix(const int* __restrict__ binc, const int* __restrict__ btot,
                       const int* __restrict__ boffs, int* __restrict__ bbase, int nbuk){
  int i=blockIdx.x*256+threadIdx.x;
  if(i<nbuk) bbase[i] = binc[i] + boffs[i>>8] - btot[i];
}

// in-place: chunk_hist[i][c] -> bbase[i] + sum_{c'<c} chunk_hist[i][c']
__global__ void k_cscan(int* __restrict__ chunk_hist, const int* __restrict__ bbase, int nbuk){
  __shared__ int s[256];
  int b=blockIdx.x; if(b>=nbuk) return;
  int x=threadIdx.x;
  int v=chunk_hist[(size_t)b*256+x];
  s[x]=v; __syncthreads();
  for(int off=1; off<256; off<<=1){
    int t=(x>=off)? s[x-off]:0; __syncthreads();
    s[x]+=t; __syncthreads();
  }
  chunk_hist[(size_t)b*256+x] = s[x]-v + bbase[b];
}

__global__ void k_bscat(const int* __restrict__ src, const int* __restrict__ dst,
                        const int* __restrict__ cbase, uint2* __restrict__ ebuf,
                        int E, int nbuk, int epc){
  __shared__ int cur[1600];
  for(int i=threadIdx.x;i<nbuk;i+=1024) cur[i]=cbase[(size_t)i*256 + blockIdx.x];
  __syncthreads();
  int base=blockIdx.x*epc, end=min(base+epc,E);
  for(int e=base+(int)threadIdx.x; e<end; e+=1024){
    int d=dst[e], s=src[e];
    int p=atomicAdd(&cur[d>>6],1);                 // LDS atomic, chunk-private region
    ebuf[p]=make_uint2((unsigned)s,(unsigned)d);
  }
}

// deg via per-bucket LDS histogram over the bucket's contiguous edge slice (no global atomics)
__global__ void k_degf(const uint2* __restrict__ ebuf, const int* __restrict__ bbase,
                       const int* __restrict__ btot, int* __restrict__ deg, int N){
  __shared__ int cnt[64];
  int b=blockIdx.x;
  if(threadIdx.x<64) cnt[threadIdx.x]=0;
  __syncthreads();
  int e0=bbase[b], e1=e0+btot[b];
  for(int e=e0+(int)threadIdx.x; e<e1; e+=256) atomicAdd(&cnt[ebuf[e].y & 63],1);
  __syncthreads();
  int n=b*64+(int)threadIdx.x;
  if(threadIdx.x<64 && n<N) deg[n]=cnt[threadIdx.x];
}

// CSR fill via per-bucket LDS cursors (no global atomics)
__global__ void k_fill3(const uint2* __restrict__ ebuf, const int* __restrict__ bbase,
                        const int* __restrict__ btot, const int* __restrict__ row_ptr,
                        int* __restrict__ csr_src, int N){
  __shared__ int cur[64];
  __shared__ int rp[64];
  int b=blockIdx.x;
  int n=b*64+(int)threadIdx.x;
  if(threadIdx.x<64){
    cur[threadIdx.x]=0;
    rp[threadIdx.x] = (n<N)? row_ptr[n] : 0;
  }
  __syncthreads();
  int e0=bbase[b], e1=e0+btot[b];
  for(int e=e0+(int)threadIdx.x; e<e1; e+=256){
    uint2 p=ebuf[e];
    int li=(int)(p.y & 63);
    int idx=atomicAdd(&cur[li],1);                 // LDS atomic
    csr_src[rp[li]+idx]=(int)p.x;
  }
}

// -------- weight prep: f32 [K][64] -> bf16 WT [64][Kp] (transposed, padded) --------
__global__ void k_prep(const float* __restrict__ W0, const float* __restrict__ Ws0,
                       const float* __restrict__ W1, const float* __restrict__ Ws1,
                       const float* __restrict__ W2, const float* __restrict__ Ws2,
                       const float* __restrict__ Wmix,
                       bf16* __restrict__ WT0, bf16* __restrict__ WT1,
                       bf16* __restrict__ WT2, bf16* __restrict__ WTm){
  int idx = blockIdx.x*256 + threadIdx.x;
  if(idx < 57344){                                   // layer0, K=128, Kp=136
    int w = idx >> 13, r = idx & 8191;
    int k = r >> 6, n = r & 63;
    float v = (w==0)? Ws0[(k<<6)+n] : W0[(((6-w)<<7) + k)*64 + n];
    WT0[(size_t)((w<<6)+n)*136 + k] = f2b(v);
  } else if(idx < 57344+28672){                      // layer1, K=64, Kp=72
    int i2 = idx - 57344;
    int w = i2 >> 12, r = i2 & 4095;
    int k = r >> 6, n = r & 63;
    float v = (w==0)? Ws1[(k<<6)+n] : W1[(((6-w)<<6) + k)*64 + n];
    WT1[(size_t)((w<<6)+n)*72 + k] = f2b(v);
  } else if(idx < 57344+2*28672){                    // layer2
    int i2 = idx - (57344+28672);
    int w = i2 >> 12, r = i2 & 4095;
    int k = r >> 6, n = r & 63;
    float v = (w==0)? Ws2[(k<<6)+n] : W2[(((6-w)<<6) + k)*64 + n];
    WT2[(size_t)((w<<6)+n)*72 + k] = f2b(v);
  } else if(idx < 57344+2*28672+12288){              // mix, K=192, Kp=200
    int i2 = idx - (57344+2*28672);
    int n = i2 / 192, k = i2 % 192;
    float v = (n<32)? Wmix[k*32 + n] : Wmix[6144 + k*32 + (n-32)];
    WTm[(size_t)n*200 + k] = f2b(v);
  }
}

// -------- MFMA mega-GEMM: BM=128, 4 waves (2x2), wave-tile 64x32, 16x16x32 bf16 --------
template<int K, int NW, int AMODE>
__global__ __launch_bounds__(256,2) void k_mfma(
    const bf16* __restrict__ Ab, const float* __restrict__ Af, const bf16* __restrict__ WT,
    bf16* __restrict__ O0, bf16* __restrict__ O1, bf16* __restrict__ O2, bf16* __restrict__ O3,
    bf16* __restrict__ O4, bf16* __restrict__ O5, bf16* __restrict__ O6,
    float* __restrict__ Zf, const float* __restrict__ dis, int M)
{
  constexpr int Kp = K + 8;
  static_assert(Kp % 8 == 0, "Kp must keep 16B alignment");
  constexpr int NS = K / 32;                 // K-slices per MFMA chain
  constexpr int NSLOT = (NW>1) ? 2 : 1;
  __shared__ short sA[128][Kp];
  __shared__ short sW[NSLOT][64][Kp];

  const int t    = threadIdx.x;
  const int m0   = blockIdx.x * 128;
  const int l    = t & 63;
  const int wid  = t >> 6;
  const int wrow = (wid >> 1) * 64;          // wave row base in tile
  const int wcol = (wid & 1) * 32;           // wave col base
  const int l4   = l & 15;
  const int lk8  = (l >> 4) * 8;             // contiguous-8 k sub-offset (m97-verified layout)

  bf16* const Ol[7] = {O0,O1,O2,O3,O4,O5,O6};
  const short8v szero = {0,0,0,0,0,0,0,0};
  const f32x4   fzero = {0.f,0.f,0.f,0.f};

  constexpr int WCH = (64*Kp)/8;             // 16B chunks per W tile
  constexpr int WIT = (WCH + 255)/256;
  short8v wreg[WIT];
  auto loadW = [&](int w){
    #pragma unroll
    for(int it=0; it<WIT; ++it){
      int c = t + it*256;
      if(c < WCH) wreg[it] = *reinterpret_cast<const short8v*>(&WT[(size_t)w*(64*Kp) + (size_t)c*8]);
    }
  };
  auto writeW = [&](int slot){
    short* base = &sW[slot][0][0];
    #pragma unroll
    for(int it=0; it<WIT; ++it){
      int c = t + it*256;
      if(c < WCH) *reinterpret_cast<short8v*>(base + (size_t)c*8) = wreg[it];
    }
  };

  loadW(0);   // global loads in flight while we stage A

  {
    constexpr int CPR = K/8;                 // 16B chunks per row
    #pragma unroll
    for(int it=0; it<(128*CPR)/256; ++it){
      int c = t + it*256;
      int row = c / CPR, j = c % CPR;
      int m = m0 + row;
      short8v v = szero;
      if(m < M){
        if constexpr(AMODE==0){
          v = *reinterpret_cast<const short8v*>(&Ab[(size_t)m*K + j*8]);
        } else if constexpr(AMODE==1){
          float4 f0 = *reinterpret_cast<const float4*>(&Af[(size_t)m*K + j*8]);
          float4 f1 = *reinterpret_cast<const float4*>(&Af[(size_t)m*K + j*8 + 4]);
          bf16* hp = reinterpret_cast<bf16*>(&v);
          hp[0]=f2b(f0.x); hp[1]=f2b(f0.y); hp[2]=f2b(f0.z); hp[3]=f2b(f0.w);
          hp[4]=f2b(f1.x); hp[5]=f2b(f1.y); hp[6]=f2b(f1.z); hp[7]=f2b(f1.w);
        } else {                             // mix: j<8 -> hA (64 bf16), else x (128 f32)
          if(j < 8){
            v = *reinterpret_cast<const short8v*>(&Ab[(size_t)m*64 + j*8]);
          } else {
            float4 f0 = *reinterpret_cast<const float4*>(&Af[(size_t)m*128 + (j-8)*8]);
            float4 f1 = *reinterpret_cast<const float4*>(&Af[(size_t)m*128 + (j-8)*8 + 4]);
            bf16* hp = reinterpret_cast<bf16*>(&v);
            hp[0]=f2b(f0.x); hp[1]=f2b(f0.y); hp[2]=f2b(f0.z); hp[3]=f2b(f0.w);
            hp[4]=f2b(f1.x); hp[5]=f2b(f1.y); hp[6]=f2b(f1.z); hp[7]=f2b(f1.w);
          }
        }
      }
      *reinterpret_cast<short8v*>(&sA[row][j*8]) = v;
    }
  }

  writeW(0);
  __syncthreads();

  short8v af[4][(NS>0)?NS:1];
  if constexpr(NW > 1){
    #pragma unroll
    for(int rt=0; rt<4; ++rt)
      #pragma unroll
      for(int s=0; s<NS; ++s)
        af[rt][s] = *reinterpret_cast<const short8v*>(&sA[wrow + rt*16 + l4][s*32 + lk8]);
  }

  #pragma unroll
  for(int w=0; w<NW; ++w){
    if(w+1 < NW) loadW(w+1);                 // issue early; consumed by writeW after compute

    f32x4 acc[4][2];
    #pragma unroll
    for(int rt=0; rt<4; ++rt){ acc[rt][0]=fzero; acc[rt][1]=fzero; }

    const short* wb = &sW[(NW>1)?(w&1):0][0][0];
    #pragma unroll
    for(int s=0; s<NS; ++s){
      short8v b0 = *reinterpret_cast<const short8v*>(wb + (size_t)(wcol +      l4)*Kp + s*32 + lk8);
      short8v b1 = *reinterpret_cast<const short8v*>(wb + (size_t)(wcol + 16 + l4)*Kp + s*32 + lk8);
      #pragma unroll
      for(int rt=0; rt<4; ++rt){
        short8v a = (NW>1) ? af[rt][s]
                  : *reinterpret_cast<const short8v*>(&sA[wrow + rt*16 + l4][s*32 + lk8]);
        acc[rt][0] = __builtin_amdgcn_mfma_f32_16x16x32_bf16(a, b0, acc[rt][0], 0,0,0);
        acc[rt][1] = __builtin_amdgcn_mfma_f32_16x16x32_bf16(a, b1, acc[rt][1], 0,0,0);
      }
    }

    if(w+1 < NW){ writeW((w+1)&1); __syncthreads(); }

    // ---- store (C/D: col = l&15, row = (l>>4)*4 + reg  [m89/m91-verified]) ----
    #pragma unroll
    for(int rt=0; rt<4; ++rt){
      #pragma unroll
      for(int r=0; r<4; ++r){
        int row = m0 + wrow + rt*16 + ((l>>4)<<2) + r;
        if(row < M){
          if constexpr(AMODE != 2){
            float sc = 1.f;
            if(NW>1 && w==1) sc = dis[row];  // P0s is the dis-scaled gather twin
            #pragma unroll
            for(int ct=0; ct<2; ++ct){
              float vv = acc[rt][ct][r] * sc;
              Ol[w][(size_t)row*64 + wcol + ct*16 + l4] = f2b(vv);
            }
          } else {                            // mix: cols 0..31 -> Zf (f32); 32..63 -> O0 bf16 *dis
            float dm = dis[row];
            #pragma unroll
            for(int ct=0; ct<2; ++ct){
              int col = wcol + ct*16 + l4;
              float vv = acc[rt][ct][r];
              if(col < 32) Zf[(size_t)row*32 + col] = vv;
              else         O0[(size_t)row*32 + (col-32)] = f2b(vv*dm);
            }
          }
        }
      }
    }
  }
}

// ---------------- sparse prop + Clenshaw combine ----------------
// [r8: 78.7us/hop, issue-bound.] r9: 8 lanes/node, uint4 gathers -> hops now < 69us
// (out of top-5, r11). Math bit-identical.
// MODE 0: r = Z - 2a                         -> store SCALED (dis[v]*r)
// MODE 1: r = Z - 2a - BsubS*dinv            -> store SCALED
// MODE 2: r = relu(Z - a - BsubS*dinv + bias) + Zs + bias2 -> store normal bf16
// MODE 3: r = Z - a + bias                   -> store normal f32
template<int F, int MODE, typename ZT, typename OT>
__global__ __launch_bounds__(256) void k_prop(const int* __restrict__ row_ptr, const int* __restrict__ csr_src,
    const float* __restrict__ dis, const float* __restrict__ dinv, const bf16* __restrict__ BinS,
    const ZT* __restrict__ Z, const bf16* __restrict__ BsubS,
    const float* __restrict__ bias, const bf16* __restrict__ Zs, const float* __restrict__ bias2,
    OT* __restrict__ out, int N){
  constexpr int L   = F/8;          // lanes per node; lane owns 8 features (1 uint4 of bf16-pairs)
  constexpr int NPB = 256/L;        // nodes per block
  int v = blockIdx.x*NPB + threadIdx.x/L;
  if(v>=N) return;
  int fl = threadIdx.x % L;
  const uint4* __restrict__ B4 = reinterpret_cast<const uint4*>(BinS);
  int e0=row_ptr[v], e1=row_ptr[v+1];
  unsigned q = (unsigned)v*L + fl;  // uint4 index into N x F bf16 streams

  // epilogue operands early (latency overlaps the gather chain)
  float z[8];
  if constexpr(MODE==3){
    const float* zp = reinterpret_cast<const float*>(Z) + (size_t)v*F + fl*8;
    float4 a=*reinterpret_cast<const float4*>(zp), b=*reinterpret_cast<const float4*>(zp+4);
    z[0]=a.x; z[1]=a.y; z[2]=a.z; z[3]=a.w; z[4]=b.x; z[5]=b.y; z[6]=b.z; z[7]=b.w;
  } else {
    unp8(reinterpret_cast<const uint4*>(Z)[q], z);
  }
  float bs[8]={};
  if constexpr(MODE==1 || MODE==2) unp8(reinterpret_cast<const uint4*>(BsubS)[q], bs);
  float bi[8]={};
  if constexpr(MODE>=2){
    float4 a=*reinterpret_cast<const float4*>(bias + fl*8);
    float4 b=*reinterpret_cast<const float4*>(bias + fl*8 + 4);
    bi[0]=a.x; bi[1]=a.y; bi[2]=a.z; bi[3]=a.w; bi[4]=b.x; bi[5]=b.y; bi[6]=b.z; bi[7]=b.w;
  }
  float zs[8]={}, b2[8]={};
  if constexpr(MODE==2){
    unp8(reinterpret_cast<const uint4*>(Zs)[q], zs);
    float4 a=*reinterpret_cast<const float4*>(bias2 + fl*8);
    float4 b=*reinterpret_cast<const float4*>(bias2 + fl*8 + 4);
    b2[0]=a.x; b2[1]=a.y; b2[2]=a.z; b2[3]=a.w; b2[4]=b.x; b2[5]=b.y; b2[6]=b.z; b2[7]=b.w;
  }
  float dv = dis[v];
  float di = dinv[v];

  float acc[8]={};
  int e=e0;
  // paired chunks: both index loads issue upfront (one exposed latency per 2L edges)
  for(; e+2*L<=e1; e+=2*L){
    int si0 = csr_src[e + fl];
    int si1 = csr_src[e + L + fl];
    uint4 g0[L], g1[L];
    #pragma unroll
    for(int j=0;j<L;++j){ int s=__shfl(si0,j,L); g0[j]=B4[(size_t)s*L+fl]; }
    #pragma unroll
    for(int j=0;j<L;++j){ int s=__shfl(si1,j,L); g1[j]=B4[(size_t)s*L+fl]; }
    #pragma unroll
    for(int j=0;j<L;++j) add8(g0[j], acc);
    #pragma unroll
    for(int j=0;j<L;++j) add8(g1[j], acc);
  }
  if(e+L<=e1){
    int si = csr_src[e + fl];
    uint4 g[L];
    #pragma unroll
    for(int j=0;j<L;++j){ int s=__shfl(si,j,L); g[j]=B4[(size_t)s*L+fl]; }
    #pragma unroll
    for(int j=0;j<L;++j) add8(g[j], acc);
    e+=L;
  }
  if(e<e1){                          // tail: 1..L-1 edges, broadcast loads, predicated
    #pragma unroll
    for(int j=0;j<L-1;++j){
      int idx=e+j;
      int s=csr_src[idx<e1 ? idx : e0];
      uint4 g=B4[(size_t)s*L+fl];
      if(idx<e1) add8(g, acc);
    }
  }

  float r[8];
  #pragma unroll
  for(int i=0;i<8;++i){
    float a = dv*acc[i];            // a = dis[v] * sum (BinS pre-scaled by dis[src])
    if constexpr(MODE==0)      r[i] = z[i] - 2.f*a;
    else if constexpr(MODE==1) r[i] = z[i] - 2.f*a - bs[i]*di;
    else if constexpr(MODE==2){ float tv = z[i] - a - bs[i]*di + bi[i];
                                r[i] = fmaxf(tv,0.f) + zs[i] + b2[i]; }
    else                       r[i] = z[i] - a + bi[i];
    if constexpr(MODE<=1) r[i] *= dv;   // scaled store (single stream)
  }
  if constexpr(MODE==3){
    float* op = reinterpret_cast<float*>(out) + (size_t)v*F + fl*8;
    *reinterpret_cast<float4*>(op)   = make_float4(r[0],r[1],r[2],r[3]);
    *reinterpret_cast<float4*>(op+4) = make_float4(r[4],r[5],r[6],r[7]);
  } else {
    reinterpret_cast<uint4*>(out)[q] = pk4(r);
  }
}

// ---------------- host ----------------

extern "C" void kernel_launch(void* const* d_in, const int* in_sizes, int n_in,
                              void* d_out, int out_size, void* d_ws, size_t ws_size,
                              hipStream_t stream) {
  const int N = in_sizes[0]/128;     // 100000
  const int E = in_sizes[1]/2;       // 3200000

  const float* x    = (const float*)d_in[0];
  const int*   ei   = (const int*  )d_in[1];
  const float* W0   = (const float*)d_in[2];
  const float* b0   = (const float*)d_in[3];
  const float* Ws0  = (const float*)d_in[4];
  const float* bs0  = (const float*)d_in[5];
  const float* W1   = (const float*)d_in[6];
  const float* b1   = (const float*)d_in[7];
  const float* Ws1  = (const float*)d_in[8];
  const float* bs1  = (const float*)d_in[9];
  const float* W2   = (const float*)d_in[10];
  const float* b2   = (const float*)d_in[11];
  const float* Ws2  = (const float*)d_in[12];
  const float* bs2  = (const float*)d_in[13];
  const float* Wmix = (const float*)d_in[14];
  const float* bmix = (const float*)d_in[15];
  float* out = (float*)d_out;

  const int* src = ei;
  const int* dst = ei + E;

  size_t off=0;
  char* ws=(char*)d_ws;
  auto alloc=[&](size_t bytes)->void*{ void* p = ws+off; off=(off+bytes+255)&~(size_t)255; return p; };
  int*   csr_src = (int*)  alloc((size_t)E*4);
  int*   row_ptr = (int*)  alloc((size_t)(N+1)*4);
  int*   deg     = (int*)  alloc((size_t)N*4);
  float* dis     = (float*)alloc((size_t)N*4);
  float* dinv    = (float*)alloc((size_t)N*4);
  int*   bsums   = (int*)  alloc(2048);
  int*   boffs   = (int*)  alloc(2048);
  bf16*  Z0      = (bf16*) alloc((size_t)N*64*2);
  bf16*  Z1      = (bf16*) alloc((size_t)N*64*2);  // reused as f32 N*32 for mix Z0
  bf16*  Z2      = (bf16*) alloc((size_t)N*64*2);
  bf16*  Z3      = (bf16*) alloc((size_t)N*64*2);
  bf16*  Z4      = (bf16*) alloc((size_t)N*64*2);
  bf16*  Zsb     = (bf16*) alloc((size_t)N*64*2);
  bf16*  P0s     = (bf16*) alloc((size_t)N*64*2);
  bf16*  P1s     = (bf16*) alloc((size_t)N*64*2);
  bf16*  P2s     = (bf16*) alloc((size_t)N*64*2);
  bf16*  hA      = (bf16*) alloc((size_t)N*64*2);
  bf16*  hB      = (bf16*) alloc((size_t)N*64*2);
  bf16*  WT0     = (bf16*) alloc((size_t)7*64*136*2);   // layer0 weights, transposed+padded bf16
  bf16*  WT1     = (bf16*) alloc((size_t)7*64*72*2);
  bf16*  WT2     = (bf16*) alloc((size_t)7*64*72*2);
  bf16*  WTm     = (bf16*) alloc((size_t)64*200*2);
  if(off > ws_size){
    fprintf(stderr, "kernel_launch: workspace too small: need %zu, have %zu\n", off, ws_size);
    return;
  }

  const int NB   = (N+255)/256;
  const int gE   = (E+255)/256;
  const int gM   = (N+127)/128;
  const int gP64 = (N+31)/32;    // k_prop<64>: 8 lanes/node, 32 nodes/block
  const int gP32 = (N+63)/64;    // k_prop<32>: 4 lanes/node, 64 nodes/block

  // bucketed-fill scratch: overlays Z0..Z2 (written only before first GEMM output)
  const int nbuk = (N+63)>>6;
  const int NB2  = (nbuk+255)/256;
  const int epc  = (E+255)/256;
  const bool fast_fill = (nbuk <= 1600);
  char*  gs         = (char*)Z0;
  uint2* ebuf       = (uint2*)gs;
  int*   chunk_hist = (int*)(gs + (((size_t)E*8 + 255) & ~(size_t)255));
  int*   binc       = chunk_hist + (size_t)nbuk*256;
  int*   btot       = binc + nbuk;
  int*   bbase      = btot + nbuk;

  // weight prep (independent of graph data)
  k_prep<<<496,256,0,stream>>>(W0,Ws0,W1,Ws1,W2,Ws2,Wmix, WT0,WT1,WT2,WTm);

  // graph prep (fast path: ZERO global atomics)
  if(fast_fill){
    hipMemsetAsync(btot, 0, (size_t)nbuk*4, stream);
    k_hist<<<256,1024,0,stream>>>(dst, chunk_hist, btot, E, nbuk, epc);
    k_scan1<<<NB2,256,0,stream>>>(btot, binc, bsums, nbuk);
    k_scan2<<<1,512,0,stream>>>(bsums, boffs, NB2);
    k_bfix<<<NB2,256,0,stream>>>(binc, btot, boffs, bbase, nbuk);
    k_cscan<<<nbuk,256,0,stream>>>(chunk_hist, bbase, nbuk);
    k_bscat<<<256,1024,0,stream>>>(src, dst, chunk_hist, ebuf, E, nbuk, epc);
    k_degf<<<nbuk,256,0,stream>>>(ebuf, bbase, btot, deg, N);
    k_scan1<<<NB,256,0,stream>>>(deg, row_ptr+1, bsums, N);
    k_scan2<<<1,512,0,stream>>>(bsums, boffs, NB);
    k_scan3<<<NB,256,0,stream>>>(row_ptr, boffs, deg, dis, dinv, N);
    k_fill3<<<nbuk,256,0,stream>>>(ebuf, bbase, btot, row_ptr, csr_src, N);
  } else {
    hipMemsetAsync(deg, 0, (size_t)N*4, stream);
    k_count<<<gE,256,0,stream>>>(dst, deg, E);
    k_scan1<<<NB,256,0,stream>>>(deg, row_ptr+1, bsums, N);
    k_scan2<<<1,512,0,stream>>>(bsums, boffs, NB);
    k_scan3<<<NB,256,0,stream>>>(row_ptr, boffs, deg, dis, dinv, N);
    k_fill<<<gE,256,0,stream>>>(src, dst, row_ptr, deg, csr_src, E);
  }

  auto PROPS=[&](const float* b, const float* bs_, bf16* hout){
    k_prop<64,0,bf16,bf16><<<gP64,256,0,stream>>>(row_ptr,csr_src,dis,dinv,P0s,Z4,nullptr,nullptr,nullptr,nullptr,P1s,N); // B4
    k_prop<64,1,bf16,bf16><<<gP64,256,0,stream>>>(row_ptr,csr_src,dis,dinv,P1s,Z3,P0s,nullptr,nullptr,nullptr,P2s,N);     // B3
    k_prop<64,1,bf16,bf16><<<gP64,256,0,stream>>>(row_ptr,csr_src,dis,dinv,P2s,Z2,P1s,nullptr,nullptr,nullptr,P0s,N);     // B2
    k_prop<64,1,bf16,bf16><<<gP64,256,0,stream>>>(row_ptr,csr_src,dis,dinv,P0s,Z1,P2s,nullptr,nullptr,nullptr,P1s,N);     // B1
    k_prop<64,2,bf16,bf16><<<gP64,256,0,stream>>>(row_ptr,csr_src,dis,dinv,P1s,Z0,P0s,b,Zsb,bs_,hout,N);                  // h'
  };

  // layer 0: A = x (f32, cvt on the fly), K=128
  k_mfma<128,7,1><<<gM,256,0,stream>>>(nullptr, x, WT0, Zsb,P0s,Z4,Z3,Z2,Z1,Z0, nullptr, dis, N);
  PROPS(b0, bs0, hA);
  // layer 1: A = hA bf16, K=64
  k_mfma<64,7,0><<<gM,256,0,stream>>>(hA, nullptr, WT1, Zsb,P0s,Z4,Z3,Z2,Z1,Z0, nullptr, dis, N);
  PROPS(b1, bs1, hB);
  // layer 2
  k_mfma<64,7,0><<<gM,256,0,stream>>>(hB, nullptr, WT2, Zsb,P0s,Z4,Z3,Z2,Z1,Z0, nullptr, dis, N);
  PROPS(b2, bs2, hA);

  // mix head: A = [hA | x] (K=192); cols 0..31 -> Zmixf (f32), cols 32..63 -> P0s (bf16, *dis)
  float* Zmixf = (float*)Z1;   // Z1 free after layer-2 props
  k_mfma<192,1,2><<<gM,256,0,stream>>>(hA, x, WTm, P0s,nullptr,nullptr,nullptr,nullptr,nullptr,nullptr, Zmixf, dis, N);
  k_prop<32,3,float,float><<<gP32,256,0,stream>>>(row_ptr,csr_src,dis,dinv,P0s,Zmixf,nullptr,bmix,nullptr,nullptr,out,N);
}